// Round 3
// baseline (1284.410 us; speedup 1.0000x reference)
//
#include <hip/hip_runtime.h>

// GatedLTMMemory: B=4, N=1024 (4096 rows), QD=320, D=512, S=1024, H=8, K=32, DH=64
// Input/output dtype detected at runtime (fp32 vs bf16) via ln_g == ones:
// fp32 word 0x3F800000 (low16==0) vs bf16 pair 0x3F803F80 (low16!=0).
//
// Algebra:
//   scores = X @ KW^T,  KW[s,:] = (1/||keys_s||) * (keys_s @ Wqp)   (fp64 -> exact ranking)
//   qh     = X @ M^T,   M = Wq @ Wqp                                 (fp32)
//   Kp = diag(1/||k||) keys @ Wk^T,  Vp = diag(1/||v||) vals @ Wv^T  (fp32, gathered later)

__device__ __forceinline__ float bf2f(unsigned short u) {
    return __uint_as_float(((unsigned int)u) << 16);
}
__device__ __forceinline__ unsigned short f2bf(float f) {
    unsigned int u = __float_as_uint(f);
    u += 0x7FFFu + ((u >> 16) & 1u);   // RNE
    return (unsigned short)(u >> 16);
}
__device__ __forceinline__ float ldg1(const void* p, size_t i, int bf) {
    return bf ? bf2f(((const unsigned short*)p)[i]) : ((const float*)p)[i];
}
__device__ __forceinline__ void ld4(const void* p, size_t i, int bf, float* o) {
    if (bf) {
        ushort4 v = *reinterpret_cast<const ushort4*>((const unsigned short*)p + i);
        o[0] = bf2f(v.x); o[1] = bf2f(v.y); o[2] = bf2f(v.z); o[3] = bf2f(v.w);
    } else {
        float4 v = *reinterpret_cast<const float4*>((const float*)p + i);
        o[0] = v.x; o[1] = v.y; o[2] = v.z; o[3] = v.w;
    }
}

__global__ void detect_kernel(const void* __restrict__ g, int* __restrict__ flag)
{
    if (threadIdx.x == 0) {
        unsigned int w = *(const unsigned int*)g;
        *flag = ((w & 0xFFFFu) != 0u) ? 1 : 0;
    }
}

__global__ __launch_bounds__(256) void norms_kernel(
    const void* __restrict__ keys, const void* __restrict__ vals,
    const int* __restrict__ flagp,
    double* __restrict__ inv_kd, float* __restrict__ inv_kf, float* __restrict__ inv_vf)
{
    __shared__ double red[256];
    int bf = *flagp;
    int r = blockIdx.x, t = threadIdx.x;
    const void* src = (r < 1024) ? keys : vals;
    size_t base = (size_t)((r < 1024) ? r : r - 1024) * 512;
    float x0 = ldg1(src, base + t, bf), x1 = ldg1(src, base + t + 256, bf);
    red[t] = (double)x0 * x0 + (double)x1 * x1;
    __syncthreads();
    for (int s = 128; s > 0; s >>= 1) {
        if (t < s) red[t] += red[t + s];
        __syncthreads();
    }
    if (t == 0) {
        double rs = 1.0 / sqrt(red[0] + 1e-12);
        if (r < 1024) { inv_kd[r] = rs; inv_kf[r] = (float)rs; }
        else          { inv_vf[r - 1024] = (float)rs; }
    }
}

__global__ __launch_bounds__(320) void kw_kernel(
    const void* __restrict__ keys, const void* __restrict__ Wqp,
    const int* __restrict__ flagp, const double* __restrict__ inv_kd,
    double* __restrict__ KW)
{
    __shared__ float row[512];
    int bf = *flagp;
    int s = blockIdx.x, t = threadIdx.x;
    for (int i = t; i < 512; i += 320) row[i] = ldg1(keys, (size_t)s * 512 + i, bf);
    __syncthreads();
    double acc = 0.0;
    for (int d = 0; d < 512; d++)
        acc += (double)row[d] * (double)ldg1(Wqp, (size_t)d * 320 + t, bf);
    KW[(size_t)s * 320 + t] = acc * inv_kd[s];
}

__global__ __launch_bounds__(320) void mfuse_kernel(
    const void* __restrict__ Wq, const void* __restrict__ Wqp,
    const int* __restrict__ flagp, float* __restrict__ Mf)
{
    __shared__ float row[512];
    int bf = *flagp;
    int e = blockIdx.x, t = threadIdx.x;
    for (int i = t; i < 512; i += 320) row[i] = ldg1(Wq, (size_t)e * 512 + i, bf);
    __syncthreads();
    float acc = 0.f;
    for (int d = 0; d < 512; d++)
        acc += row[d] * ldg1(Wqp, (size_t)d * 320 + t, bf);
    Mf[(size_t)e * 320 + t] = acc;
}

// Sc[512 x 1024] (double) = X[row0+.. , :] @ KW^T ; row0 = chunk base row.
__global__ __launch_bounds__(256) void gemm_scores(
    const void* __restrict__ X, int row0, const int* __restrict__ flagp,
    const double* __restrict__ KW, double* __restrict__ Sc)
{
    constexpr int BM = 128, BN = 64, BK = 16;
    __shared__ float  As[BK][BM + 1];
    __shared__ double Bs[BK][BN + 1];
    int bf = *flagp;
    int t = threadIdx.x;
    int m0 = blockIdx.y * BM, n0 = blockIdx.x * BN;
    int ar = t >> 1, ak = (t & 1) * 8;
    int br = t >> 2, bk = (t & 3) * 4;
    int ty = t >> 4, tx = t & 15;
    double acc[8][4];
#pragma unroll
    for (int j = 0; j < 8; j++)
#pragma unroll
        for (int i = 0; i < 4; i++) acc[j][i] = 0.0;
    for (int k0 = 0; k0 < 320; k0 += BK) {
        float av[8];
        ld4(X, (size_t)(row0 + m0 + ar) * 320 + k0 + ak,     bf, av);
        ld4(X, (size_t)(row0 + m0 + ar) * 320 + k0 + ak + 4, bf, av + 4);
        double b0 = KW[(size_t)(n0 + br) * 320 + k0 + bk];
        double b1 = KW[(size_t)(n0 + br) * 320 + k0 + bk + 1];
        double b2 = KW[(size_t)(n0 + br) * 320 + k0 + bk + 2];
        double b3 = KW[(size_t)(n0 + br) * 320 + k0 + bk + 3];
#pragma unroll
        for (int j = 0; j < 8; j++) As[ak + j][ar] = av[j];
        Bs[bk + 0][br] = b0; Bs[bk + 1][br] = b1;
        Bs[bk + 2][br] = b2; Bs[bk + 3][br] = b3;
        __syncthreads();
#pragma unroll
        for (int k = 0; k < BK; k++) {
            float a[8]; double b[4];
#pragma unroll
            for (int j = 0; j < 8; j++) a[j] = As[k][ty * 8 + j];
#pragma unroll
            for (int i = 0; i < 4; i++) b[i] = Bs[k][tx * 4 + i];
#pragma unroll
            for (int j = 0; j < 8; j++)
#pragma unroll
                for (int i = 0; i < 4; i++) acc[j][i] += (double)a[j] * b[i];
        }
        __syncthreads();
    }
#pragma unroll
    for (int j = 0; j < 8; j++)
#pragma unroll
        for (int i = 0; i < 4; i++)
            Sc[(size_t)(m0 + ty * 8 + j) * 1024 + n0 + tx * 4 + i] = acc[j][i];
}

__global__ __launch_bounds__(256) void topk_kernel(
    const double* __restrict__ Sc, int* __restrict__ idx)
{
    __shared__ double sv[1024];
    __shared__ double bv[256];
    __shared__ int    bi[256];
    int row = blockIdx.x, t = threadIdx.x;
    for (int i = t; i < 1024; i += 256) sv[i] = Sc[(size_t)row * 1024 + i];
    __syncthreads();
    for (int it = 0; it < 32; it++) {
        double best = -1e300; int besti = 0;
        for (int i = t; i < 1024; i += 256) {
            double v = sv[i];
            if (v > best) { best = v; besti = i; }
        }
        bv[t] = best; bi[t] = besti;
        __syncthreads();
        for (int s = 128; s > 0; s >>= 1) {
            if (t < s) {
                double v2 = bv[t + s]; int i2 = bi[t + s];
                if (v2 > bv[t] || (v2 == bv[t] && i2 < bi[t])) { bv[t] = v2; bi[t] = i2; }
            }
            __syncthreads();
        }
        if (t == 0) {
            idx[(size_t)row * 32 + it] = bi[0];
            sv[bi[0]] = -1e300;
        }
        __syncthreads();
    }
}

// C = [rowscale(A)] @ B^T. amode/bmode: 1 -> dtype follows *flagp, 0 -> fp32.
// epi 0: fp32 -> C. epi 1: (+bias) -> O in *flagp dtype.
__global__ __launch_bounds__(256) void gemm_abt(
    const void* __restrict__ A, const void* __restrict__ B,
    const float* __restrict__ As_scale,
    float* __restrict__ C, const void* __restrict__ bias, void* __restrict__ O,
    int M, int N, int K, int amode, int bmode, int epi,
    const int* __restrict__ flagp)
{
    constexpr int BM = 128, BN = 64, BK = 16;
    __shared__ float As[BK][BM + 1];
    __shared__ float Bs[BK][BN + 1];
    const int flag = *flagp;
    const int abf = amode ? flag : 0;
    const int bbf = bmode ? flag : 0;
    const int t  = threadIdx.x;
    const int m0 = blockIdx.y * BM, n0 = blockIdx.x * BN;
    const int ar = t >> 1, ak = (t & 1) * 8;
    const int br = t >> 2, bk = (t & 3) * 4;
    const int ty = t >> 4, tx = t & 15;
    const float sc = As_scale ? As_scale[m0 + ar] : 1.0f;

    float acc[8][4];
#pragma unroll
    for (int j = 0; j < 8; j++)
#pragma unroll
        for (int i = 0; i < 4; i++) acc[j][i] = 0.f;

    for (int k0 = 0; k0 < K; k0 += BK) {
        float av[8], bv4[4];
        ld4(A, (size_t)(m0 + ar) * K + k0 + ak,     abf, av);
        ld4(A, (size_t)(m0 + ar) * K + k0 + ak + 4, abf, av + 4);
        ld4(B, (size_t)(n0 + br) * K + k0 + bk,     bbf, bv4);
#pragma unroll
        for (int j = 0; j < 8; j++) As[ak + j][ar] = av[j] * sc;
#pragma unroll
        for (int j = 0; j < 4; j++) Bs[bk + j][br] = bv4[j];
        __syncthreads();
#pragma unroll
        for (int k = 0; k < BK; k++) {
            float a[8], b[4];
#pragma unroll
            for (int j = 0; j < 8; j++) a[j] = As[k][ty * 8 + j];
#pragma unroll
            for (int i = 0; i < 4; i++) b[i] = Bs[k][tx * 4 + i];
#pragma unroll
            for (int j = 0; j < 8; j++)
#pragma unroll
                for (int i = 0; i < 4; i++) acc[j][i] += a[j] * b[i];
        }
        __syncthreads();
    }

#pragma unroll
    for (int j = 0; j < 8; j++) {
        int m = m0 + ty * 8 + j;
#pragma unroll
        for (int i = 0; i < 4; i++) {
            int n = n0 + tx * 4 + i;
            float v = acc[j][i];
            size_t off = (size_t)m * N + n;
            if (epi == 0) {
                C[off] = v;
            } else {
                if (bias) v += ldg1(bias, n, flag);
                if (flag) ((unsigned short*)O)[off] = f2bf(v);
                else      ((float*)O)[off] = v;
            }
        }
    }
}

__global__ __launch_bounds__(256) void attn_kernel(
    const float* __restrict__ qh, const float* __restrict__ Kp,
    const float* __restrict__ Vp, const int* __restrict__ idx,
    float* __restrict__ ctx)
{
    __shared__ float sq[512];
    __shared__ int   sidx[32];
    __shared__ float sl[8][32];
    __shared__ float sw[8][32];
    int row = blockIdx.x, t = threadIdx.x;
    sq[t]       = qh[(size_t)row * 512 + t];
    sq[t + 256] = qh[(size_t)row * 512 + 256 + t];
    if (t < 32) {
        int v = idx[(size_t)row * 32 + t];
        sidx[t] = (v < 0) ? 0 : (v > 1023 ? 1023 : v);
    }
    __syncthreads();

    int h = t >> 5, k = t & 31;
    const float* kp = Kp + (size_t)sidx[k] * 512 + h * 64;
    float acc = 0.f;
#pragma unroll
    for (int d = 0; d < 64; d++) acc += sq[h * 64 + d] * kp[d];
    float logit = acc * 0.125f;
    sl[h][k] = logit;
    __syncthreads();
    float m = -1e30f;
#pragma unroll
    for (int i = 0; i < 32; i++) m = fmaxf(m, sl[h][i]);
    float ssum = 0.f;
#pragma unroll
    for (int i = 0; i < 32; i++) ssum += __expf(sl[h][i] - m);
    sw[h][k] = __expf(logit - m) / ssum;
    __syncthreads();

#pragma unroll
    for (int rep = 0; rep < 2; rep++) {
        int c = t + rep * 256;
        int hh = c >> 6;
        float a = 0.f;
#pragma unroll
        for (int kk = 0; kk < 32; kk++)
            a += sw[hh][kk] * Vp[(size_t)sidx[kk] * 512 + c];
        ctx[(size_t)row * 512 + c] = a;
    }
}

__global__ __launch_bounds__(256) void ln_kernel(
    const float* __restrict__ co, const void* __restrict__ g,
    const void* __restrict__ b, const int* __restrict__ flagp,
    float* __restrict__ o)
{
    __shared__ double ra[256], rb[256];
    int bf = *flagp;
    int r = blockIdx.x, t = threadIdx.x;
    float x0 = co[(size_t)r * 512 + t], x1 = co[(size_t)r * 512 + 256 + t];
    ra[t] = (double)x0 + (double)x1;
    rb[t] = (double)x0 * x0 + (double)x1 * x1;
    __syncthreads();
    for (int s = 128; s > 0; s >>= 1) {
        if (t < s) { ra[t] += ra[t + s]; rb[t] += rb[t + s]; }
        __syncthreads();
    }
    __shared__ float smu, sinv;
    if (t == 0) {
        double mu = ra[0] / 512.0, var = rb[0] / 512.0 - mu * mu;
        smu = (float)mu;
        sinv = (float)(1.0 / sqrt(var + 1e-5));
    }
    __syncthreads();
    o[(size_t)r * 512 + t]       = (x0 - smu) * sinv * ldg1(g, t, bf)       + ldg1(b, t, bf);
    o[(size_t)r * 512 + 256 + t] = (x1 - smu) * sinv * ldg1(g, 256 + t, bf) + ldg1(b, 256 + t, bf);
}

extern "C" void kernel_launch(void* const* d_in, const int* in_sizes, int n_in,
                              void* d_out, int out_size, void* d_ws, size_t ws_size,
                              hipStream_t stream)
{
    const void* X    = d_in[0];
    const void* Wqp  = d_in[1];
    const void* keys = d_in[2];
    const void* vals = d_in[3];
    const void* Wq   = d_in[4];
    const void* Wk   = d_in[5];
    const void* Wv   = d_in[6];
    const void* Wo   = d_in[7];
    const void* ln_g = d_in[8];
    const void* ln_b = d_in[9];
    const void* Wout = d_in[10];
    const void* bout = d_in[11];

    float* ws = (float*)d_ws;
    float*  qh     = ws;                              // 2,097,152 fl; reused as co
    float*  ctx    = ws + 2097152;                    // 2,097,152 fl; reused as normed
    double* chunkD = (double*)(ws + 4194304);         // 512*1024 dbl
    float*  Kp     = ws + 4194304;                    // 524,288 fl (reuse chunk region)
    float*  Vp     = ws + 4718592;                    // 524,288 fl
    double* KW     = (double*)(ws + 5242880);         // 1024*320 dbl
    float*  Mf     = ws + 5242880;                    // 512*320 fl (reuse after scores)
    int*    idx    = (int*)(ws + 5898240);            // 4096*32 int
    double* inv_kd = (double*)(ws + 6029312);
    float*  inv_kf = ws + 6031360;
    float*  inv_vf = ws + 6032384;
    int*    flag   = (int*)(ws + 6033408);
    float*  co     = qh;
    float*  normed = ctx;

    detect_kernel<<<1, 64, 0, stream>>>(ln_g, flag);
    norms_kernel<<<2048, 256, 0, stream>>>(keys, vals, flag, inv_kd, inv_kf, inv_vf);
    kw_kernel<<<1024, 320, 0, stream>>>(keys, Wqp, flag, inv_kd, KW);
    for (int c = 0; c < 8; c++) {
        gemm_scores<<<dim3(16, 4), 256, 0, stream>>>(X, c * 512, flag, KW, chunkD);
        topk_kernel<<<512, 256, 0, stream>>>(chunkD, idx + (size_t)c * 512 * 32);
    }
    mfuse_kernel<<<512, 320, 0, stream>>>(Wq, Wqp, flag, Mf);
    gemm_abt<<<dim3(8, 32), 256, 0, stream>>>(
        X, Mf, nullptr, qh, nullptr, nullptr, 4096, 512, 320, 1, 0, 0, flag);
    gemm_abt<<<dim3(8, 8), 256, 0, stream>>>(
        keys, Wk, inv_kf, Kp, nullptr, nullptr, 1024, 512, 512, 1, 1, 0, flag);
    gemm_abt<<<dim3(8, 8), 256, 0, stream>>>(
        vals, Wv, inv_vf, Vp, nullptr, nullptr, 1024, 512, 512, 1, 1, 0, flag);
    attn_kernel<<<4096, 256, 0, stream>>>(qh, Kp, Vp, idx, ctx);
    gemm_abt<<<dim3(8, 32), 256, 0, stream>>>(
        ctx, Wo, nullptr, co, nullptr, nullptr, 4096, 512, 512, 0, 1, 0, flag);
    ln_kernel<<<4096, 256, 0, stream>>>(co, ln_g, ln_b, flag, normed);
    gemm_abt<<<dim3(5, 32), 256, 0, stream>>>(
        normed, Wout, nullptr, nullptr, bout, d_out, 4096, 320, 512, 0, 1, 1, flag);
}

// Round 4
// 518.121 us; speedup vs baseline: 2.4790x; 2.4790x over previous
//
#include <hip/hip_runtime.h>

// GatedLTMMemory: 4096 rows, QD=320, D=512, S=1024, H=8, K=32, DH=64
// Runtime dtype detect (fp32 vs bf16) via ln_g==ones. Round 3 resolved: fp32.
//
// Algebra:
//   scores = X @ KW^T,  KW[s,:] = (1/||keys_s||)*(keys_s @ Wqp)  (fp64 acc, fp32 store)
//   qh     = X @ Mf^T,  Mf = Wq @ Wqp                            (fp32)
//   Kp = diag(1/||k||) keys @ Wk^T,  Vp likewise                 (fp32, gathered later)

__device__ __forceinline__ float bf2f(unsigned short u) {
    return __uint_as_float(((unsigned int)u) << 16);
}
__device__ __forceinline__ unsigned short f2bf(float f) {
    unsigned int u = __float_as_uint(f);
    u += 0x7FFFu + ((u >> 16) & 1u);
    return (unsigned short)(u >> 16);
}
__device__ __forceinline__ float ldg1(const void* p, size_t i, int bf) {
    return bf ? bf2f(((const unsigned short*)p)[i]) : ((const float*)p)[i];
}
__device__ __forceinline__ void ld4(const void* p, size_t i, int bf, float* o) {
    if (bf) {
        ushort4 v = *reinterpret_cast<const ushort4*>((const unsigned short*)p + i);
        o[0] = bf2f(v.x); o[1] = bf2f(v.y); o[2] = bf2f(v.z); o[3] = bf2f(v.w);
    } else {
        float4 v = *reinterpret_cast<const float4*>((const float*)p + i);
        o[0] = v.x; o[1] = v.y; o[2] = v.z; o[3] = v.w;
    }
}

__global__ void detect_kernel(const void* __restrict__ g, int* __restrict__ flag)
{
    if (threadIdx.x == 0) {
        unsigned int w = *(const unsigned int*)g;
        *flag = ((w & 0xFFFFu) != 0u) ? 1 : 0;
    }
}

__global__ __launch_bounds__(256) void norms_kernel(
    const void* __restrict__ keys, const void* __restrict__ vals,
    const int* __restrict__ flagp,
    double* __restrict__ inv_kd, float* __restrict__ inv_kf, float* __restrict__ inv_vf)
{
    __shared__ double red[256];
    int bf = *flagp;
    int r = blockIdx.x, t = threadIdx.x;
    const void* src = (r < 1024) ? keys : vals;
    size_t base = (size_t)((r < 1024) ? r : r - 1024) * 512;
    float x0 = ldg1(src, base + t, bf), x1 = ldg1(src, base + t + 256, bf);
    red[t] = (double)x0 * x0 + (double)x1 * x1;
    __syncthreads();
    for (int s = 128; s > 0; s >>= 1) {
        if (t < s) red[t] += red[t + s];
        __syncthreads();
    }
    if (t == 0) {
        double rs = 1.0 / sqrt(red[0] + 1e-12);
        if (r < 1024) { inv_kd[r] = rs; inv_kf[r] = (float)rs; }
        else          { inv_vf[r - 1024] = (float)rs; }
    }
}

// ---------------------------------------------------------------------------
// C = A @ B (B row-major [K,N]). A is flag-dtype. OUTD 0: fp32 C. OUTD 1: fp64 C
// scaled by inv_kd[row]. BM=BN=64, BK=32, 256 threads, 4x4 micro.
// ---------------------------------------------------------------------------
template<int OUTD>
__global__ __launch_bounds__(256) void gemm_ab(
    const void* __restrict__ A, const void* __restrict__ B,
    const int* __restrict__ flagp, const double* __restrict__ inv_kd,
    float* __restrict__ Cf, double* __restrict__ Cd, int M, int N, int K)
{
    __shared__ float As[32][68];
    __shared__ float Bs[32][68];
    const int bf = *flagp;
    const int t = threadIdx.x;
    const int m0 = blockIdx.y * 64, n0 = blockIdx.x * 64;
    const int r = t & 63, kc = (t >> 6) * 8;          // A stage
    const int tx = t & 15, kr = t >> 4;               // B stage (kr 0..15)
    const int ty = t >> 4;                            // micro rows
    float acc[4][4];
#pragma unroll
    for (int j = 0; j < 4; j++)
#pragma unroll
        for (int i = 0; i < 4; i++) acc[j][i] = 0.f;

    for (int k0 = 0; k0 < K; k0 += 32) {
        float av[8], bv0[4], bv1[4];
        ld4(A, (size_t)(m0 + r) * K + k0 + kc,     bf, av);
        ld4(A, (size_t)(m0 + r) * K + k0 + kc + 4, bf, av + 4);
        ld4(B, (size_t)(k0 + kr) * N + n0 + tx * 4,      bf, bv0);
        ld4(B, (size_t)(k0 + kr + 16) * N + n0 + tx * 4, bf, bv1);
#pragma unroll
        for (int j = 0; j < 8; j++) As[kc + j][r] = av[j];
        *reinterpret_cast<float4*>(&Bs[kr][tx * 4])      = make_float4(bv0[0], bv0[1], bv0[2], bv0[3]);
        *reinterpret_cast<float4*>(&Bs[kr + 16][tx * 4]) = make_float4(bv1[0], bv1[1], bv1[2], bv1[3]);
        __syncthreads();
#pragma unroll
        for (int k = 0; k < 32; k++) {
            float4 a = *reinterpret_cast<const float4*>(&As[k][ty * 4]);
            float4 b = *reinterpret_cast<const float4*>(&Bs[k][tx * 4]);
            float aa[4] = {a.x, a.y, a.z, a.w}, bb[4] = {b.x, b.y, b.z, b.w};
#pragma unroll
            for (int j = 0; j < 4; j++)
#pragma unroll
                for (int i = 0; i < 4; i++) acc[j][i] += aa[j] * bb[i];
        }
        __syncthreads();
    }
#pragma unroll
    for (int j = 0; j < 4; j++) {
        int m = m0 + ty * 4 + j;
#pragma unroll
        for (int i = 0; i < 4; i++) {
            int n = n0 + tx * 4 + i;
            if (OUTD == 0) Cf[(size_t)m * N + n] = acc[j][i];
            else           Cd[(size_t)m * N + n] = (double)acc[j][i] * inv_kd[m];
        }
    }
}

// Specialized fp64-accurate kw: KW = rowscale(keys) @ Wqp in fp64 end-to-end.
__global__ __launch_bounds__(256) void gemm_ab_f64(
    const void* __restrict__ A, const void* __restrict__ B,
    const int* __restrict__ flagp, const double* __restrict__ inv_kd,
    double* __restrict__ Cd, int M, int N, int K)
{
    __shared__ float As[32][68];
    __shared__ float Bs[32][68];
    const int bf = *flagp;
    const int t = threadIdx.x;
    const int m0 = blockIdx.y * 64, n0 = blockIdx.x * 64;
    const int r = t & 63, kc = (t >> 6) * 8;
    const int tx = t & 15, kr = t >> 4;
    const int ty = t >> 4;
    double acc[4][4];
#pragma unroll
    for (int j = 0; j < 4; j++)
#pragma unroll
        for (int i = 0; i < 4; i++) acc[j][i] = 0.0;

    for (int k0 = 0; k0 < K; k0 += 32) {
        float av[8], bv0[4], bv1[4];
        ld4(A, (size_t)(m0 + r) * K + k0 + kc,     bf, av);
        ld4(A, (size_t)(m0 + r) * K + k0 + kc + 4, bf, av + 4);
        ld4(B, (size_t)(k0 + kr) * N + n0 + tx * 4,      bf, bv0);
        ld4(B, (size_t)(k0 + kr + 16) * N + n0 + tx * 4, bf, bv1);
#pragma unroll
        for (int j = 0; j < 8; j++) As[kc + j][r] = av[j];
        *reinterpret_cast<float4*>(&Bs[kr][tx * 4])      = make_float4(bv0[0], bv0[1], bv0[2], bv0[3]);
        *reinterpret_cast<float4*>(&Bs[kr + 16][tx * 4]) = make_float4(bv1[0], bv1[1], bv1[2], bv1[3]);
        __syncthreads();
#pragma unroll
        for (int k = 0; k < 32; k++) {
            float4 a = *reinterpret_cast<const float4*>(&As[k][ty * 4]);
            float4 b = *reinterpret_cast<const float4*>(&Bs[k][tx * 4]);
            float aa[4] = {a.x, a.y, a.z, a.w}, bb[4] = {b.x, b.y, b.z, b.w};
#pragma unroll
            for (int j = 0; j < 4; j++)
#pragma unroll
                for (int i = 0; i < 4; i++) acc[j][i] += (double)aa[j] * (double)bb[i];
        }
        __syncthreads();
    }
#pragma unroll
    for (int j = 0; j < 4; j++) {
        int m = m0 + ty * 4 + j;
#pragma unroll
        for (int i = 0; i < 4; i++)
            Cd[(size_t)m * N + n0 + tx * 4 + i] = acc[j][i] * inv_kd[m];
    }
}

// ---------------------------------------------------------------------------
// Scores chunk: Sc[2048 x 1024] fp32 = X[row0.., :320] @ KW^T (KW fp64, fp64 acc).
// ---------------------------------------------------------------------------
__global__ __launch_bounds__(256) void gemm_scores(
    const void* __restrict__ X, int row0, const int* __restrict__ flagp,
    const double* __restrict__ KW, float* __restrict__ Sc)
{
    __shared__ float  As[32][68];
    __shared__ double Bs[32][68];
    const int bf = *flagp;
    const int t = threadIdx.x;
    const int m0 = blockIdx.y * 64, n0 = blockIdx.x * 64;
    const int r = t & 63, kc = (t >> 6) * 8;
    const int tx = t & 15, ty = t >> 4;
    double acc[4][4];
#pragma unroll
    for (int j = 0; j < 4; j++)
#pragma unroll
        for (int i = 0; i < 4; i++) acc[j][i] = 0.0;

    for (int k0 = 0; k0 < 320; k0 += 32) {
        float av[8];
        ld4(X, (size_t)(row0 + m0 + r) * 320 + k0 + kc,     bf, av);
        ld4(X, (size_t)(row0 + m0 + r) * 320 + k0 + kc + 4, bf, av + 4);
        double bd[8];
#pragma unroll
        for (int j = 0; j < 8; j += 2) {
            double2 d = *reinterpret_cast<const double2*>(KW + (size_t)(n0 + r) * 320 + k0 + kc + j);
            bd[j] = d.x; bd[j + 1] = d.y;
        }
#pragma unroll
        for (int j = 0; j < 8; j++) As[kc + j][r] = av[j];
#pragma unroll
        for (int j = 0; j < 8; j++) Bs[kc + j][r] = bd[j];
        __syncthreads();
#pragma unroll
        for (int k = 0; k < 32; k++) {
            float4 a = *reinterpret_cast<const float4*>(&As[k][ty * 4]);
            double2 b0 = *reinterpret_cast<const double2*>(&Bs[k][tx * 4]);
            double2 b1 = *reinterpret_cast<const double2*>(&Bs[k][tx * 4 + 2]);
            float aa[4] = {a.x, a.y, a.z, a.w};
            double bb[4] = {b0.x, b0.y, b1.x, b1.y};
#pragma unroll
            for (int j = 0; j < 4; j++)
#pragma unroll
                for (int i = 0; i < 4; i++) acc[j][i] += (double)aa[j] * bb[i];
        }
        __syncthreads();
    }
#pragma unroll
    for (int j = 0; j < 4; j++) {
        float4 o = make_float4((float)acc[j][0], (float)acc[j][1],
                               (float)acc[j][2], (float)acc[j][3]);
        *reinterpret_cast<float4*>(&Sc[(size_t)(m0 + ty * 4 + j) * 1024 + n0 + tx * 4]) = o;
    }
}

// ---------------------------------------------------------------------------
// Top-32 per row: one wave per row. 16 vals/lane, bitonic sort-16 in registers,
// then 32x butterfly argmax (tie -> lower index), shift-down heads.
// ---------------------------------------------------------------------------
__global__ __launch_bounds__(256) void topk_wave(
    const float* __restrict__ Sc, int* __restrict__ idx)
{
    int w = threadIdx.x >> 6, lane = threadIdx.x & 63;
    int row = blockIdx.x * 4 + w;
    const float* S = Sc + (size_t)row * 1024;
    float v[16]; int id[16];
#pragma unroll
    for (int j = 0; j < 16; j++) { int c = j * 64 + lane; v[j] = S[c]; id[j] = c; }
    // bitonic sort, descending by (v desc, id asc) — ids unique -> total order
#pragma unroll
    for (int k = 2; k <= 16; k <<= 1) {
#pragma unroll
        for (int jj = k >> 1; jj > 0; jj >>= 1) {
#pragma unroll
            for (int i = 0; i < 16; i++) {
                int l = i ^ jj;
                if (l > i) {
                    bool gt_li = (v[l] > v[i]) || (v[l] == v[i] && id[l] < id[i]);
                    bool sw = ((i & k) == 0) ? gt_li : !gt_li;
                    if (sw) {
                        float tv = v[i]; v[i] = v[l]; v[l] = tv;
                        int ti = id[i]; id[i] = id[l]; id[l] = ti;
                    }
                }
            }
        }
    }
    for (int it = 0; it < 32; it++) {
        float bv = v[0]; int bi = id[0];
#pragma unroll
        for (int m = 1; m < 64; m <<= 1) {
            float ov = __shfl_xor(bv, m, 64);
            int   oi = __shfl_xor(bi, m, 64);
            if (ov > bv || (ov == bv && oi < bi)) { bv = ov; bi = oi; }
        }
        if (lane == 0) idx[(size_t)row * 32 + it] = bi;
        bool adv = (id[0] == bi);
#pragma unroll
        for (int j = 0; j < 15; j++) {
            v[j]  = adv ? v[j + 1]  : v[j];
            id[j] = adv ? id[j + 1] : id[j];
        }
        if (adv) { v[15] = -INFINITY; id[15] = 0x7FFFFFFF; }
    }
}

// ---------------------------------------------------------------------------
// C = [rowscale(A)] @ B^T. BM=BN=64, BK=32, 256 threads, 4x4 micro, float4 LDS.
// amode/bmode: 1 -> flag dtype, 0 -> fp32. epi 0: fp32 C. epi 1: (+bias) -> flag-dtype O.
// ---------------------------------------------------------------------------
__global__ __launch_bounds__(256) void gemm_abt(
    const void* __restrict__ A, const void* __restrict__ B,
    const float* __restrict__ As_scale,
    float* __restrict__ C, const void* __restrict__ bias, void* __restrict__ O,
    int M, int N, int K, int amode, int bmode, int epi,
    const int* __restrict__ flagp)
{
    __shared__ float As[32][68];
    __shared__ float Bs[32][68];
    const int flag = *flagp;
    const int abf = amode ? flag : 0;
    const int bbf = bmode ? flag : 0;
    const int t = threadIdx.x;
    const int m0 = blockIdx.y * 64, n0 = blockIdx.x * 64;
    const int r = t & 63, kc = (t >> 6) * 8;
    const int tx = t & 15, ty = t >> 4;
    const float sc = As_scale ? As_scale[m0 + r] : 1.0f;
    float acc[4][4];
#pragma unroll
    for (int j = 0; j < 4; j++)
#pragma unroll
        for (int i = 0; i < 4; i++) acc[j][i] = 0.f;

    for (int k0 = 0; k0 < K; k0 += 32) {
        float av[8], bv[8];
        ld4(A, (size_t)(m0 + r) * K + k0 + kc,     abf, av);
        ld4(A, (size_t)(m0 + r) * K + k0 + kc + 4, abf, av + 4);
        ld4(B, (size_t)(n0 + r) * K + k0 + kc,     bbf, bv);
        ld4(B, (size_t)(n0 + r) * K + k0 + kc + 4, bbf, bv + 4);
#pragma unroll
        for (int j = 0; j < 8; j++) As[kc + j][r] = av[j] * sc;
#pragma unroll
        for (int j = 0; j < 8; j++) Bs[kc + j][r] = bv[j];
        __syncthreads();
#pragma unroll
        for (int k = 0; k < 32; k++) {
            float4 a = *reinterpret_cast<const float4*>(&As[k][ty * 4]);
            float4 b = *reinterpret_cast<const float4*>(&Bs[k][tx * 4]);
            float aa[4] = {a.x, a.y, a.z, a.w}, bb[4] = {b.x, b.y, b.z, b.w};
#pragma unroll
            for (int j = 0; j < 4; j++)
#pragma unroll
                for (int i = 0; i < 4; i++) acc[j][i] += aa[j] * bb[i];
        }
        __syncthreads();
    }
#pragma unroll
    for (int j = 0; j < 4; j++) {
        int m = m0 + ty * 4 + j;
        int n = n0 + tx * 4;
        size_t off = (size_t)m * N + n;
        if (epi == 0) {
            *reinterpret_cast<float4*>(&C[off]) =
                make_float4(acc[j][0], acc[j][1], acc[j][2], acc[j][3]);
        } else {
            float o4[4];
#pragma unroll
            for (int i = 0; i < 4; i++)
                o4[i] = acc[j][i] + (bias ? ldg1(bias, n + i, flag) : 0.f);
            if (flag) {
                ushort4 u = make_ushort4(f2bf(o4[0]), f2bf(o4[1]), f2bf(o4[2]), f2bf(o4[3]));
                *reinterpret_cast<ushort4*>((unsigned short*)O + off) = u;
            } else {
                *reinterpret_cast<float4*>((float*)O + off) =
                    make_float4(o4[0], o4[1], o4[2], o4[3]);
            }
        }
    }
}

// ---------------------------------------------------------------------------
// Fused gather + 8-head attention per row (unchanged from round 3 — verified).
// ---------------------------------------------------------------------------
__global__ __launch_bounds__(256) void attn_kernel(
    const float* __restrict__ qh, const float* __restrict__ Kp,
    const float* __restrict__ Vp, const int* __restrict__ idx,
    float* __restrict__ ctx)
{
    __shared__ float sq[512];
    __shared__ int   sidx[32];
    __shared__ float sl[8][32];
    __shared__ float sw[8][32];
    int row = blockIdx.x, t = threadIdx.x;
    sq[t]       = qh[(size_t)row * 512 + t];
    sq[t + 256] = qh[(size_t)row * 512 + 256 + t];
    if (t < 32) {
        int v = idx[(size_t)row * 32 + t];
        sidx[t] = (v < 0) ? 0 : (v > 1023 ? 1023 : v);
    }
    __syncthreads();

    int h = t >> 5, k = t & 31;
    const float* kp = Kp + (size_t)sidx[k] * 512 + h * 64;
    float acc = 0.f;
#pragma unroll
    for (int d = 0; d < 64; d++) acc += sq[h * 64 + d] * kp[d];
    float logit = acc * 0.125f;
    sl[h][k] = logit;
    __syncthreads();
    float m = -1e30f;
#pragma unroll
    for (int i = 0; i < 32; i++) m = fmaxf(m, sl[h][i]);
    float ssum = 0.f;
#pragma unroll
    for (int i = 0; i < 32; i++) ssum += __expf(sl[h][i] - m);
    sw[h][k] = __expf(logit - m) / ssum;
    __syncthreads();

#pragma unroll
    for (int rep = 0; rep < 2; rep++) {
        int c = t + rep * 256;
        int hh = c >> 6;
        float a = 0.f;
#pragma unroll
        for (int kk = 0; kk < 32; kk++)
            a += sw[hh][kk] * Vp[(size_t)sidx[kk] * 512 + c];
        ctx[(size_t)row * 512 + c] = a;
    }
}

__global__ __launch_bounds__(256) void ln_kernel(
    const float* __restrict__ co, const void* __restrict__ g,
    const void* __restrict__ b, const int* __restrict__ flagp,
    float* __restrict__ o)
{
    __shared__ double ra[256], rb[256];
    int bf = *flagp;
    int r = blockIdx.x, t = threadIdx.x;
    float x0 = co[(size_t)r * 512 + t], x1 = co[(size_t)r * 512 + 256 + t];
    ra[t] = (double)x0 + (double)x1;
    rb[t] = (double)x0 * x0 + (double)x1 * x1;
    __syncthreads();
    for (int s = 128; s > 0; s >>= 1) {
        if (t < s) { ra[t] += ra[t + s]; rb[t] += rb[t + s]; }
        __syncthreads();
    }
    __shared__ float smu, sinv;
    if (t == 0) {
        double mu = ra[0] / 512.0, var = rb[0] / 512.0 - mu * mu;
        smu = (float)mu;
        sinv = (float)(1.0 / sqrt(var + 1e-5));
    }
    __syncthreads();
    o[(size_t)r * 512 + t]       = (x0 - smu) * sinv * ldg1(g, t, bf)       + ldg1(b, t, bf);
    o[(size_t)r * 512 + 256 + t] = (x1 - smu) * sinv * ldg1(g, 256 + t, bf) + ldg1(b, 256 + t, bf);
}

extern "C" void kernel_launch(void* const* d_in, const int* in_sizes, int n_in,
                              void* d_out, int out_size, void* d_ws, size_t ws_size,
                              hipStream_t stream)
{
    const void* X    = d_in[0];
    const void* Wqp  = d_in[1];
    const void* keys = d_in[2];
    const void* vals = d_in[3];
    const void* Wq   = d_in[4];
    const void* Wk   = d_in[5];
    const void* Wv   = d_in[6];
    const void* Wo   = d_in[7];
    const void* ln_g = d_in[8];
    const void* ln_b = d_in[9];
    const void* Wout = d_in[10];
    const void* bout = d_in[11];

    // ---- workspace (float units; total 6,033,409 fl ~= 23.0 MiB) ----
    float* ws = (float*)d_ws;
    float*  Xreg   = ws;                       // 2,097,152: qh -> co
    float*  Yreg   = ws + 2097152;             // 2,097,152: scores chunk -> ctx -> normed
    float*  Kp     = ws + 4194304;             // 524,288
    float*  Vp     = ws + 4718592;             // 524,288
    double* KW     = (double*)(ws + 5242880);  // 1024*320 dbl (655,360 fl); Mf aliases
    float*  Mf     = ws + 5242880;             // 512*320 fl (after scores done)
    int*    idx    = (int*)(ws + 5898240);     // 131,072
    double* inv_kd = (double*)(ws + 6029312);  // 2,048 fl
    float*  inv_kf = ws + 6031360;
    float*  inv_vf = ws + 6032384;
    int*    flag   = (int*)(ws + 6033408);
    float*  qh     = Xreg;
    float*  co     = Xreg;                     // qh dead after attn
    float*  Sc     = Yreg;                     // 2048x1024 fp32 chunk
    float*  ctx    = Yreg;                     // Sc dead after topk
    float*  normed = Yreg;                     // ctx dead after Wo-gemm

    detect_kernel<<<1, 64, 0, stream>>>(ln_g, flag);
    norms_kernel<<<2048, 256, 0, stream>>>(keys, vals, flag, inv_kd, inv_kf, inv_vf);
    // KW = rowscale(keys) @ Wqp, fp64 acc: grid (320/64, 1024/64)
    gemm_ab_f64<<<dim3(5, 16), 256, 0, stream>>>(keys, Wqp, flag, inv_kd, KW, 1024, 320, 512);
    // scores (fp64 acc, fp32 store) + topk, 2 chunks of 2048 rows
    for (int c = 0; c < 2; c++) {
        gemm_scores<<<dim3(16, 32), 256, 0, stream>>>(X, c * 2048, flag, KW, Sc);
        topk_wave<<<512, 256, 0, stream>>>(Sc, idx + (size_t)c * 2048 * 32);
    }
    // Mf = Wq @ Wqp (fp32): grid (5, 8)
    gemm_ab<0><<<dim3(5, 8), 256, 0, stream>>>(Wq, Wqp, flag, nullptr, Mf, nullptr, 512, 320, 512);
    // qh = X @ Mf^T: grid (512/64, 4096/64) = (8, 64)
    gemm_abt<<<dim3(8, 64), 256, 0, stream>>>(
        X, Mf, nullptr, qh, nullptr, nullptr, 4096, 512, 320, 1, 0, 0, flag);
    // Kp/Vp = rowscale(keys|vals) @ Wk^T|Wv^T: grid (8, 16)
    gemm_abt<<<dim3(8, 16), 256, 0, stream>>>(
        keys, Wk, inv_kf, Kp, nullptr, nullptr, 1024, 512, 512, 1, 1, 0, flag);
    gemm_abt<<<dim3(8, 16), 256, 0, stream>>>(
        vals, Wv, inv_vf, Vp, nullptr, nullptr, 1024, 512, 512, 1, 1, 0, flag);
    attn_kernel<<<4096, 256, 0, stream>>>(qh, Kp, Vp, idx, ctx);
    // co = ctx @ Wo^T: grid (8, 64)
    gemm_abt<<<dim3(8, 64), 256, 0, stream>>>(
        ctx, Wo, nullptr, co, nullptr, nullptr, 4096, 512, 512, 0, 1, 0, flag);
    ln_kernel<<<4096, 256, 0, stream>>>(co, ln_g, ln_b, flag, normed);
    // out = normed @ Wout^T + bout: grid (320/64, 64) = (5, 64)
    gemm_abt<<<dim3(5, 64), 256, 0, stream>>>(
        normed, Wout, nullptr, nullptr, bout, d_out, 4096, 320, 512, 0, 1, 1, flag);
}

// Round 5
// 502.073 us; speedup vs baseline: 2.5582x; 1.0320x over previous
//
#include <hip/hip_runtime.h>

// GatedLTMMemory: 4096 rows, QD=320, D=512, S=1024, H=8, K=32, DH=64
// Runtime dtype detect (fp32 vs bf16) via ln_g==ones. (Resolved: fp32.)
//
// Algebra:
//   scores = X @ KW^T,  KW[s,:] = (1/||keys_s||)*(keys_s @ Wqp)
//     bulk in fp32 (KWf), top-48 candidates; rows with rank31/32 gap < 1e-4
//     re-scored exactly in fp64 (KW) inside topk_refine -> exact top-32 set.
//   qh = X @ Mf^T,  Mf = Wq @ Wqp          (fp32)
//   Kp = rowscale(keys) @ Wk^T, Vp likewise (fp32, gathered in attn)

__device__ __forceinline__ float bf2f(unsigned short u) {
    return __uint_as_float(((unsigned int)u) << 16);
}
__device__ __forceinline__ unsigned short f2bf(float f) {
    unsigned int u = __float_as_uint(f);
    u += 0x7FFFu + ((u >> 16) & 1u);
    return (unsigned short)(u >> 16);
}
__device__ __forceinline__ float ldg1(const void* p, size_t i, int bf) {
    return bf ? bf2f(((const unsigned short*)p)[i]) : ((const float*)p)[i];
}
__device__ __forceinline__ void ld4(const void* p, size_t i, int bf, float* o) {
    if (bf) {
        ushort4 v = *reinterpret_cast<const ushort4*>((const unsigned short*)p + i);
        o[0] = bf2f(v.x); o[1] = bf2f(v.y); o[2] = bf2f(v.z); o[3] = bf2f(v.w);
    } else {
        float4 v = *reinterpret_cast<const float4*>((const float*)p + i);
        o[0] = v.x; o[1] = v.y; o[2] = v.z; o[3] = v.w;
    }
}

__global__ void detect_kernel(const void* __restrict__ g, int* __restrict__ flag)
{
    if (threadIdx.x == 0) {
        unsigned int w = *(const unsigned int*)g;
        *flag = ((w & 0xFFFFu) != 0u) ? 1 : 0;
    }
}

__global__ __launch_bounds__(256) void norms_kernel(
    const void* __restrict__ keys, const void* __restrict__ vals,
    const int* __restrict__ flagp,
    double* __restrict__ inv_kd, float* __restrict__ inv_kf, float* __restrict__ inv_vf)
{
    __shared__ double red[256];
    int bf = *flagp;
    int r = blockIdx.x, t = threadIdx.x;
    const void* src = (r < 1024) ? keys : vals;
    size_t base = (size_t)((r < 1024) ? r : r - 1024) * 512;
    float x0 = ldg1(src, base + t, bf), x1 = ldg1(src, base + t + 256, bf);
    red[t] = (double)x0 * x0 + (double)x1 * x1;
    __syncthreads();
    for (int s = 128; s > 0; s >>= 1) {
        if (t < s) red[t] += red[t + s];
        __syncthreads();
    }
    if (t == 0) {
        double rs = 1.0 / sqrt(red[0] + 1e-12);
        if (r < 1024) { inv_kd[r] = rs; inv_kf[r] = (float)rs; }
        else          { inv_vf[r - 1024] = (float)rs; }
    }
}

// ---------------------------------------------------------------------------
// C = A @ B (B row-major [K,N]) fp32. BM=BN=64, BK=32, 256 threads, 4x4 micro.
// ---------------------------------------------------------------------------
__global__ __launch_bounds__(256) void gemm_ab(
    const void* __restrict__ A, const void* __restrict__ B,
    const int* __restrict__ flagp, float* __restrict__ Cf, int M, int N, int K)
{
    __shared__ float As[32][68];
    __shared__ float Bs[32][68];
    const int bf = *flagp;
    const int t = threadIdx.x;
    const int m0 = blockIdx.y * 64, n0 = blockIdx.x * 64;
    const int r = t & 63, kc = (t >> 6) * 8;
    const int tx = t & 15, kr = t >> 4;
    const int ty = t >> 4;
    float acc[4][4];
#pragma unroll
    for (int j = 0; j < 4; j++)
#pragma unroll
        for (int i = 0; i < 4; i++) acc[j][i] = 0.f;

    for (int k0 = 0; k0 < K; k0 += 32) {
        float av[8], bv0[4], bv1[4];
        ld4(A, (size_t)(m0 + r) * K + k0 + kc,     bf, av);
        ld4(A, (size_t)(m0 + r) * K + k0 + kc + 4, bf, av + 4);
        ld4(B, (size_t)(k0 + kr) * N + n0 + tx * 4,      bf, bv0);
        ld4(B, (size_t)(k0 + kr + 16) * N + n0 + tx * 4, bf, bv1);
#pragma unroll
        for (int j = 0; j < 8; j++) As[kc + j][r] = av[j];
        *reinterpret_cast<float4*>(&Bs[kr][tx * 4])      = make_float4(bv0[0], bv0[1], bv0[2], bv0[3]);
        *reinterpret_cast<float4*>(&Bs[kr + 16][tx * 4]) = make_float4(bv1[0], bv1[1], bv1[2], bv1[3]);
        __syncthreads();
#pragma unroll
        for (int k = 0; k < 32; k++) {
            float4 a = *reinterpret_cast<const float4*>(&As[k][ty * 4]);
            float4 b = *reinterpret_cast<const float4*>(&Bs[k][tx * 4]);
            float aa[4] = {a.x, a.y, a.z, a.w}, bb[4] = {b.x, b.y, b.z, b.w};
#pragma unroll
            for (int j = 0; j < 4; j++)
#pragma unroll
                for (int i = 0; i < 4; i++) acc[j][i] += aa[j] * bb[i];
        }
        __syncthreads();
    }
#pragma unroll
    for (int j = 0; j < 4; j++) {
        int m = m0 + ty * 4 + j;
#pragma unroll
        for (int i = 0; i < 4; i++)
            Cf[(size_t)m * N + n0 + tx * 4 + i] = acc[j][i];
    }
}

// KW = rowscale(keys) @ Wqp, fp64 accumulate; writes fp64 KW and fp32 KWf.
__global__ __launch_bounds__(256) void gemm_ab_f64(
    const void* __restrict__ A, const void* __restrict__ B,
    const int* __restrict__ flagp, const double* __restrict__ inv_kd,
    double* __restrict__ Cd, float* __restrict__ Cf, int M, int N, int K)
{
    __shared__ float As[32][68];
    __shared__ float Bs[32][68];
    const int bf = *flagp;
    const int t = threadIdx.x;
    const int m0 = blockIdx.y * 64, n0 = blockIdx.x * 64;
    const int r = t & 63, kc = (t >> 6) * 8;
    const int tx = t & 15, kr = t >> 4;
    const int ty = t >> 4;
    double acc[4][4];
#pragma unroll
    for (int j = 0; j < 4; j++)
#pragma unroll
        for (int i = 0; i < 4; i++) acc[j][i] = 0.0;

    for (int k0 = 0; k0 < K; k0 += 32) {
        float av[8], bv0[4], bv1[4];
        ld4(A, (size_t)(m0 + r) * K + k0 + kc,     bf, av);
        ld4(A, (size_t)(m0 + r) * K + k0 + kc + 4, bf, av + 4);
        ld4(B, (size_t)(k0 + kr) * N + n0 + tx * 4,      bf, bv0);
        ld4(B, (size_t)(k0 + kr + 16) * N + n0 + tx * 4, bf, bv1);
#pragma unroll
        for (int j = 0; j < 8; j++) As[kc + j][r] = av[j];
        *reinterpret_cast<float4*>(&Bs[kr][tx * 4])      = make_float4(bv0[0], bv0[1], bv0[2], bv0[3]);
        *reinterpret_cast<float4*>(&Bs[kr + 16][tx * 4]) = make_float4(bv1[0], bv1[1], bv1[2], bv1[3]);
        __syncthreads();
#pragma unroll
        for (int k = 0; k < 32; k++) {
            float4 a = *reinterpret_cast<const float4*>(&As[k][ty * 4]);
            float4 b = *reinterpret_cast<const float4*>(&Bs[k][tx * 4]);
            float aa[4] = {a.x, a.y, a.z, a.w}, bb[4] = {b.x, b.y, b.z, b.w};
#pragma unroll
            for (int j = 0; j < 4; j++)
#pragma unroll
                for (int i = 0; i < 4; i++) acc[j][i] += (double)aa[j] * (double)bb[i];
        }
        __syncthreads();
    }
#pragma unroll
    for (int j = 0; j < 4; j++) {
        int m = m0 + ty * 4 + j;
#pragma unroll
        for (int i = 0; i < 4; i++) {
            double v = acc[j][i] * inv_kd[m];
            Cd[(size_t)m * N + n0 + tx * 4 + i] = v;
            Cf[(size_t)m * N + n0 + tx * 4 + i] = (float)v;
        }
    }
}

// ---------------------------------------------------------------------------
// C = [rowscale(A)] @ B^T. BM=BN=64, BK=32, 256 threads, 4x4 micro.
// amode/bmode: 1 -> flag dtype, 0 -> fp32. epi 0: fp32 C. epi 1: (+bias)->flag O.
// ---------------------------------------------------------------------------
__global__ __launch_bounds__(256) void gemm_abt(
    const void* __restrict__ A, const void* __restrict__ B,
    const float* __restrict__ As_scale,
    float* __restrict__ C, const void* __restrict__ bias, void* __restrict__ O,
    int M, int N, int K, int amode, int bmode, int epi,
    const int* __restrict__ flagp)
{
    __shared__ float As[32][68];
    __shared__ float Bs[32][68];
    const int flag = *flagp;
    const int abf = amode ? flag : 0;
    const int bbf = bmode ? flag : 0;
    const int t = threadIdx.x;
    const int m0 = blockIdx.y * 64, n0 = blockIdx.x * 64;
    const int r = t & 63, kc = (t >> 6) * 8;
    const int tx = t & 15, ty = t >> 4;
    const float sc = As_scale ? As_scale[m0 + r] : 1.0f;
    float acc[4][4];
#pragma unroll
    for (int j = 0; j < 4; j++)
#pragma unroll
        for (int i = 0; i < 4; i++) acc[j][i] = 0.f;

    for (int k0 = 0; k0 < K; k0 += 32) {
        float av[8], bv[8];
        ld4(A, (size_t)(m0 + r) * K + k0 + kc,     abf, av);
        ld4(A, (size_t)(m0 + r) * K + k0 + kc + 4, abf, av + 4);
        ld4(B, (size_t)(n0 + r) * K + k0 + kc,     bbf, bv);
        ld4(B, (size_t)(n0 + r) * K + k0 + kc + 4, bbf, bv + 4);
#pragma unroll
        for (int j = 0; j < 8; j++) As[kc + j][r] = av[j] * sc;
#pragma unroll
        for (int j = 0; j < 8; j++) Bs[kc + j][r] = bv[j];
        __syncthreads();
#pragma unroll
        for (int k = 0; k < 32; k++) {
            float4 a = *reinterpret_cast<const float4*>(&As[k][ty * 4]);
            float4 b = *reinterpret_cast<const float4*>(&Bs[k][tx * 4]);
            float aa[4] = {a.x, a.y, a.z, a.w}, bb[4] = {b.x, b.y, b.z, b.w};
#pragma unroll
            for (int j = 0; j < 4; j++)
#pragma unroll
                for (int i = 0; i < 4; i++) acc[j][i] += aa[j] * bb[i];
        }
        __syncthreads();
    }
#pragma unroll
    for (int j = 0; j < 4; j++) {
        int m = m0 + ty * 4 + j;
        int n = n0 + tx * 4;
        size_t off = (size_t)m * N + n;
        if (epi == 0) {
            *reinterpret_cast<float4*>(&C[off]) =
                make_float4(acc[j][0], acc[j][1], acc[j][2], acc[j][3]);
        } else {
            float o4[4];
#pragma unroll
            for (int i = 0; i < 4; i++)
                o4[i] = acc[j][i] + (bias ? ldg1(bias, n + i, flag) : 0.f);
            if (flag) {
                ushort4 u = make_ushort4(f2bf(o4[0]), f2bf(o4[1]), f2bf(o4[2]), f2bf(o4[3]));
                *reinterpret_cast<ushort4*>((unsigned short*)O + off) = u;
            } else {
                *reinterpret_cast<float4*>((float*)O + off) =
                    make_float4(o4[0], o4[1], o4[2], o4[3]);
            }
        }
    }
}

// ---------------------------------------------------------------------------
// Fused top-48 (fp32) + boundary-triggered exact fp64 refine -> top-32 set.
// One wave per row; 4 rows per 256-thread block. Register/shuffle only.
// ---------------------------------------------------------------------------
__global__ __launch_bounds__(256) void topk_refine(
    const float* __restrict__ Sc, const void* __restrict__ X,
    const int* __restrict__ flagp, const double* __restrict__ KW,
    int* __restrict__ idx)
{
    const int bf = *flagp;
    int w = threadIdx.x >> 6, lane = threadIdx.x & 63;
    int row = blockIdx.x * 4 + w;
    const float* S = Sc + (size_t)row * 1024;
    float v[16]; int id[16];
#pragma unroll
    for (int j = 0; j < 16; j++) { int c = j * 64 + lane; v[j] = S[c]; id[j] = c; }
    // bitonic sort-16 descending by (v desc, id asc); ids unique -> total order
#pragma unroll
    for (int k = 2; k <= 16; k <<= 1) {
#pragma unroll
        for (int jj = k >> 1; jj > 0; jj >>= 1) {
#pragma unroll
            for (int i = 0; i < 16; i++) {
                int l = i ^ jj;
                if (l > i) {
                    bool gt_li = (v[l] > v[i]) || (v[l] == v[i] && id[l] < id[i]);
                    bool sw = ((i & k) == 0) ? gt_li : !gt_li;
                    if (sw) {
                        float tv = v[i]; v[i] = v[l]; v[l] = tv;
                        int ti = id[i]; id[i] = id[l]; id[l] = ti;
                    }
                }
            }
        }
    }
    // extract 48 candidates; lane c keeps candidate c in registers
    float mycv = -INFINITY; int myci = 0x7FFFFFFF;
    float v31 = 0.f, v32 = 0.f;
    for (int it = 0; it < 48; it++) {
        float bv = v[0]; int bi = id[0];
#pragma unroll
        for (int m = 1; m < 64; m <<= 1) {
            float ov = __shfl_xor(bv, m, 64);
            int   oi = __shfl_xor(bi, m, 64);
            if (ov > bv || (ov == bv && oi < bi)) { bv = ov; bi = oi; }
        }
        if (it == lane) { mycv = bv; myci = bi; }
        if (it == 31) v31 = bv;
        if (it == 32) v32 = bv;
        bool adv = (id[0] == bi);
#pragma unroll
        for (int j = 0; j < 15; j++) {
            v[j]  = adv ? v[j + 1]  : v[j];
            id[j] = adv ? id[j + 1] : id[j];
        }
        if (adv) { v[15] = -INFINITY; id[15] = 0x7FFFFFFF; }
    }
    // margin check: fp32 worst-case dot error ~1e-5 << 1e-4 threshold
    if (v31 - v32 > 1e-4f) {
        if (lane < 32) idx[(size_t)row * 32 + lane] = myci;
        return;
    }
    // exact fp64 rescoring of the 48 candidates
    float x[5];
#pragma unroll
    for (int j = 0; j < 5; j++) x[j] = ldg1(X, (size_t)row * 320 + lane + 64 * j, bf);
    double eval = -1.0e300; int eidx = 0x7FFFFFFF;
#pragma unroll 1
    for (int c = 0; c < 48; c++) {
        int cidx = __shfl(myci, c, 64);
        const double* kr = KW + (size_t)cidx * 320;
        double s = 0.0;
#pragma unroll
        for (int j = 0; j < 5; j++) s += (double)x[j] * kr[lane + 64 * j];
#pragma unroll
        for (int m = 1; m < 64; m <<= 1) s += __shfl_xor(s, m, 64);
        if (lane == c) { eval = s; eidx = cidx; }
    }
    for (int it = 0; it < 32; it++) {
        double bv = eval; int bi = eidx;
#pragma unroll
        for (int m = 1; m < 64; m <<= 1) {
            double ov = __shfl_xor(bv, m, 64);
            int    oi = __shfl_xor(bi, m, 64);
            if (ov > bv || (ov == bv && oi < bi)) { bv = ov; bi = oi; }
        }
        if (lane == 0) idx[(size_t)row * 32 + it] = bi;
        if (eidx == bi) { eval = -1.0e300; eidx = 0x7FFFFFFF; }
    }
}

// ---------------------------------------------------------------------------
// Fused gather + 8-head attention per row. float4 QK, float2 PV.
// ---------------------------------------------------------------------------
__global__ __launch_bounds__(256) void attn_kernel(
    const float* __restrict__ qh, const float* __restrict__ Kp,
    const float* __restrict__ Vp, const int* __restrict__ idx,
    float* __restrict__ ctx)
{
    __shared__ float sq[512];
    __shared__ int   sidx[32];
    __shared__ float sl[8][32];
    __shared__ float sw[8][32];
    int row = blockIdx.x, t = threadIdx.x;
    if (t < 128)
        *reinterpret_cast<float4*>(&sq[t * 4]) =
            *reinterpret_cast<const float4*>(&qh[(size_t)row * 512 + t * 4]);
    if (t < 32) {
        int v = idx[(size_t)row * 32 + t];
        sidx[t] = (v < 0) ? 0 : (v > 1023 ? 1023 : v);
    }
    __syncthreads();

    int h = t >> 5, k = t & 31;
    const float* kp = Kp + (size_t)sidx[k] * 512 + h * 64;
    float acc = 0.f;
#pragma unroll
    for (int d = 0; d < 16; d++) {
        float4 a = *reinterpret_cast<const float4*>(&sq[h * 64 + d * 4]);
        float4 b = *reinterpret_cast<const float4*>(&kp[d * 4]);
        acc += a.x * b.x + a.y * b.y + a.z * b.z + a.w * b.w;
    }
    float logit = acc * 0.125f;
    sl[h][k] = logit;
    __syncthreads();
    float m = -1e30f;
#pragma unroll
    for (int i = 0; i < 32; i++) m = fmaxf(m, sl[h][i]);
    float ssum = 0.f;
#pragma unroll
    for (int i = 0; i < 32; i++) ssum += __expf(sl[h][i] - m);
    sw[h][k] = __expf(logit - m) / ssum;
    __syncthreads();

    int c = t * 2, hh = c >> 6;
    float ax = 0.f, ay = 0.f;
#pragma unroll
    for (int kk = 0; kk < 32; kk++) {
        float2 vv = *reinterpret_cast<const float2*>(&Vp[(size_t)sidx[kk] * 512 + c]);
        float wgt = sw[hh][kk];
        ax += wgt * vv.x; ay += wgt * vv.y;
    }
    *reinterpret_cast<float2*>(&ctx[(size_t)row * 512 + c]) = make_float2(ax, ay);
}

__global__ __launch_bounds__(256) void ln_kernel(
    const float* __restrict__ co, const void* __restrict__ g,
    const void* __restrict__ b, const int* __restrict__ flagp,
    float* __restrict__ o)
{
    __shared__ double ra[256], rb[256];
    int bf = *flagp;
    int r = blockIdx.x, t = threadIdx.x;
    float x0 = co[(size_t)r * 512 + t], x1 = co[(size_t)r * 512 + 256 + t];
    ra[t] = (double)x0 + (double)x1;
    rb[t] = (double)x0 * x0 + (double)x1 * x1;
    __syncthreads();
    for (int s = 128; s > 0; s >>= 1) {
        if (t < s) { ra[t] += ra[t + s]; rb[t] += rb[t + s]; }
        __syncthreads();
    }
    __shared__ float smu, sinv;
    if (t == 0) {
        double mu = ra[0] / 512.0, var = rb[0] / 512.0 - mu * mu;
        smu = (float)mu;
        sinv = (float)(1.0 / sqrt(var + 1e-5));
    }
    __syncthreads();
    o[(size_t)r * 512 + t]       = (x0 - smu) * sinv * ldg1(g, t, bf)       + ldg1(b, t, bf);
    o[(size_t)r * 512 + 256 + t] = (x1 - smu) * sinv * ldg1(g, 256 + t, bf) + ldg1(b, 256 + t, bf);
}

extern "C" void kernel_launch(void* const* d_in, const int* in_sizes, int n_in,
                              void* d_out, int out_size, void* d_ws, size_t ws_size,
                              hipStream_t stream)
{
    const void* X    = d_in[0];
    const void* Wqp  = d_in[1];
    const void* keys = d_in[2];
    const void* vals = d_in[3];
    const void* Wq   = d_in[4];
    const void* Wk   = d_in[5];
    const void* Wv   = d_in[6];
    const void* Wo   = d_in[7];
    const void* ln_g = d_in[8];
    const void* ln_b = d_in[9];
    const void* Wout = d_in[10];
    const void* bout = d_in[11];

    // ---- workspace (float units; ~23.0 MiB, same as round 4) ----
    float* ws = (float*)d_ws;
    float*  Sc     = ws;                       // 4096x1024 fp32 = 4,194,304 fl
    float*  Xreg   = ws;                       // 2,097,152: qh -> co (after topk)
    float*  Yreg   = ws + 2097152;             // 2,097,152: ctx -> normed
    float*  Mf     = ws + 4194304;             // 163,840 fl (Kp region; dead pre-Kp)
    float*  Kp     = ws + 4194304;             // 524,288
    float*  KWf    = ws + 4718592;             // 327,680 fl (Vp region; dead pre-Vp)
    float*  Vp     = ws + 4718592;             // 524,288
    double* KW     = (double*)(ws + 5242880);  // 1024*320 dbl (655,360 fl)
    int*    idx    = (int*)(ws + 5898240);     // 131,072
    double* inv_kd = (double*)(ws + 6029312);  // 2,048 fl
    float*  inv_kf = ws + 6031360;
    float*  inv_vf = ws + 6032384;
    int*    flag   = (int*)(ws + 6033408);
    float*  qh     = Xreg;
    float*  co     = Xreg;                     // qh dead after attn
    float*  ctx    = Yreg;
    float*  normed = Yreg;                     // ctx dead after Wo-gemm

    detect_kernel<<<1, 64, 0, stream>>>(ln_g, flag);
    norms_kernel<<<2048, 256, 0, stream>>>(keys, vals, flag, inv_kd, inv_kf, inv_vf);
    // KW (fp64) + KWf (fp32) = rowscale(keys) @ Wqp
    gemm_ab_f64<<<dim3(5, 16), 256, 0, stream>>>(
        keys, Wqp, flag, inv_kd, KW, KWf, 1024, 320, 512);
    // Mf = Wq @ Wqp (fp32)
    gemm_ab<<<dim3(5, 8), 256, 0, stream>>>(Wq, Wqp, flag, Mf, 512, 320, 512);
    // Sc = X @ KWf^T (fp32 bulk), single full-GPU launch
    gemm_abt<<<dim3(16, 64), 256, 0, stream>>>(
        X, KWf, nullptr, Sc, nullptr, nullptr, 4096, 1024, 320, 1, 0, 0, flag);
    // top-48 + exact fp64 boundary refine -> idx (exact top-32 set)
    topk_refine<<<1024, 256, 0, stream>>>(Sc, X, flag, KW, idx);
    // qh = X @ Mf^T (overwrites Sc lower half — Sc dead)
    gemm_abt<<<dim3(8, 64), 256, 0, stream>>>(
        X, Mf, nullptr, qh, nullptr, nullptr, 4096, 512, 320, 1, 0, 0, flag);
    // Kp/Vp = rowscale(keys|vals) @ Wk^T|Wv^T (overwrite Mf / KWf — dead)
    gemm_abt<<<dim3(8, 16), 256, 0, stream>>>(
        keys, Wk, inv_kf, Kp, nullptr, nullptr, 1024, 512, 512, 1, 1, 0, flag);
    gemm_abt<<<dim3(8, 16), 256, 0, stream>>>(
        vals, Wv, inv_vf, Vp, nullptr, nullptr, 1024, 512, 512, 1, 1, 0, flag);
    attn_kernel<<<4096, 256, 0, stream>>>(qh, Kp, Vp, idx, ctx);
    gemm_abt<<<dim3(8, 64), 256, 0, stream>>>(
        ctx, Wo, nullptr, co, nullptr, nullptr, 4096, 512, 512, 0, 1, 0, flag);
    ln_kernel<<<4096, 256, 0, stream>>>(co, ln_g, ln_b, flag, normed);
    gemm_abt<<<dim3(5, 64), 256, 0, stream>>>(
        normed, Wout, nullptr, nullptr, bout, d_out, 4096, 320, 512, 0, 1, 1, flag);
}

// Round 6
// 480.864 us; speedup vs baseline: 2.6710x; 1.0441x over previous
//
#include <hip/hip_runtime.h>

// GatedLTMMemory: 4096 rows, QD=320, D=512, S=1024, H=8, K=32, DH=64
// Runtime dtype detect (fp32 vs bf16) via ln_g==ones. (Resolved: fp32.)
//
// Algebra:
//   scores = X @ KW^T,  KW[s,:] = (1/||keys_s||)*(keys_s @ Wqp)
//     bulk in fp32 (KWf); top-[33,48] candidate set via uint-bisection; rows with
//     rank32/33 gap < 1e-4 re-scored exactly in fp64 (KW) -> exact top-32 set.
//   qh = X @ Mf^T,  Mf = Wq @ Wqp          (fp32)
//   Kp = rowscale(keys) @ Wk^T, Vp likewise (fp32, gathered in attn)

__device__ __forceinline__ float bf2f(unsigned short u) {
    return __uint_as_float(((unsigned int)u) << 16);
}
__device__ __forceinline__ unsigned short f2bf(float f) {
    unsigned int u = __float_as_uint(f);
    u += 0x7FFFu + ((u >> 16) & 1u);
    return (unsigned short)(u >> 16);
}
__device__ __forceinline__ float ldg1(const void* p, size_t i, int bf) {
    return bf ? bf2f(((const unsigned short*)p)[i]) : ((const float*)p)[i];
}
__device__ __forceinline__ void ld4(const void* p, size_t i, int bf, float* o) {
    if (bf) {
        ushort4 v = *reinterpret_cast<const ushort4*>((const unsigned short*)p + i);
        o[0] = bf2f(v.x); o[1] = bf2f(v.y); o[2] = bf2f(v.z); o[3] = bf2f(v.w);
    } else {
        float4 v = *reinterpret_cast<const float4*>((const float*)p + i);
        o[0] = v.x; o[1] = v.y; o[2] = v.z; o[3] = v.w;
    }
}

__global__ void detect_kernel(const void* __restrict__ g, int* __restrict__ flag)
{
    if (threadIdx.x == 0) {
        unsigned int w = *(const unsigned int*)g;
        *flag = ((w & 0xFFFFu) != 0u) ? 1 : 0;
    }
}

__global__ __launch_bounds__(256) void norms_kernel(
    const void* __restrict__ keys, const void* __restrict__ vals,
    const int* __restrict__ flagp,
    double* __restrict__ inv_kd, float* __restrict__ inv_kf, float* __restrict__ inv_vf)
{
    __shared__ double red[256];
    int bf = *flagp;
    int r = blockIdx.x, t = threadIdx.x;
    const void* src = (r < 1024) ? keys : vals;
    size_t base = (size_t)((r < 1024) ? r : r - 1024) * 512;
    float x0 = ldg1(src, base + t, bf), x1 = ldg1(src, base + t + 256, bf);
    red[t] = (double)x0 * x0 + (double)x1 * x1;
    __syncthreads();
    for (int s = 128; s > 0; s >>= 1) {
        if (t < s) red[t] += red[t + s];
        __syncthreads();
    }
    if (t == 0) {
        double rs = 1.0 / sqrt(red[0] + 1e-12);
        if (r < 1024) { inv_kd[r] = rs; inv_kf[r] = (float)rs; }
        else          { inv_vf[r - 1024] = (float)rs; }
    }
}

// ---------------------------------------------------------------------------
// C = A @ B (B row-major [K,N]) fp32. BM=BN=64, BK=32, 256 threads, 4x4 micro.
// ---------------------------------------------------------------------------
__global__ __launch_bounds__(256) void gemm_ab(
    const void* __restrict__ A, const void* __restrict__ B,
    const int* __restrict__ flagp, float* __restrict__ Cf, int M, int N, int K)
{
    __shared__ float As[32][68];
    __shared__ float Bs[32][68];
    const int bf = *flagp;
    const int t = threadIdx.x;
    const int m0 = blockIdx.y * 64, n0 = blockIdx.x * 64;
    const int r = t & 63, kc = (t >> 6) * 8;
    const int tx = t & 15, kr = t >> 4;
    const int ty = t >> 4;
    float acc[4][4];
#pragma unroll
    for (int j = 0; j < 4; j++)
#pragma unroll
        for (int i = 0; i < 4; i++) acc[j][i] = 0.f;

    for (int k0 = 0; k0 < K; k0 += 32) {
        float av[8], bv0[4], bv1[4];
        ld4(A, (size_t)(m0 + r) * K + k0 + kc,     bf, av);
        ld4(A, (size_t)(m0 + r) * K + k0 + kc + 4, bf, av + 4);
        ld4(B, (size_t)(k0 + kr) * N + n0 + tx * 4,      bf, bv0);
        ld4(B, (size_t)(k0 + kr + 16) * N + n0 + tx * 4, bf, bv1);
#pragma unroll
        for (int j = 0; j < 8; j++) As[kc + j][r] = av[j];
        *reinterpret_cast<float4*>(&Bs[kr][tx * 4])      = make_float4(bv0[0], bv0[1], bv0[2], bv0[3]);
        *reinterpret_cast<float4*>(&Bs[kr + 16][tx * 4]) = make_float4(bv1[0], bv1[1], bv1[2], bv1[3]);
        __syncthreads();
#pragma unroll
        for (int k = 0; k < 32; k++) {
            float4 a = *reinterpret_cast<const float4*>(&As[k][ty * 4]);
            float4 b = *reinterpret_cast<const float4*>(&Bs[k][tx * 4]);
            float aa[4] = {a.x, a.y, a.z, a.w}, bb[4] = {b.x, b.y, b.z, b.w};
#pragma unroll
            for (int j = 0; j < 4; j++)
#pragma unroll
                for (int i = 0; i < 4; i++) acc[j][i] += aa[j] * bb[i];
        }
        __syncthreads();
    }
#pragma unroll
    for (int j = 0; j < 4; j++) {
        int m = m0 + ty * 4 + j;
#pragma unroll
        for (int i = 0; i < 4; i++)
            Cf[(size_t)m * N + n0 + tx * 4 + i] = acc[j][i];
    }
}

// KW = rowscale(keys) @ Wqp, fp64 accumulate; writes fp64 KW and fp32 KWf.
__global__ __launch_bounds__(256) void gemm_ab_f64(
    const void* __restrict__ A, const void* __restrict__ B,
    const int* __restrict__ flagp, const double* __restrict__ inv_kd,
    double* __restrict__ Cd, float* __restrict__ Cf, int M, int N, int K)
{
    __shared__ float As[32][68];
    __shared__ float Bs[32][68];
    const int bf = *flagp;
    const int t = threadIdx.x;
    const int m0 = blockIdx.y * 64, n0 = blockIdx.x * 64;
    const int r = t & 63, kc = (t >> 6) * 8;
    const int tx = t & 15, kr = t >> 4;
    const int ty = t >> 4;
    double acc[4][4];
#pragma unroll
    for (int j = 0; j < 4; j++)
#pragma unroll
        for (int i = 0; i < 4; i++) acc[j][i] = 0.0;

    for (int k0 = 0; k0 < K; k0 += 32) {
        float av[8], bv0[4], bv1[4];
        ld4(A, (size_t)(m0 + r) * K + k0 + kc,     bf, av);
        ld4(A, (size_t)(m0 + r) * K + k0 + kc + 4, bf, av + 4);
        ld4(B, (size_t)(k0 + kr) * N + n0 + tx * 4,      bf, bv0);
        ld4(B, (size_t)(k0 + kr + 16) * N + n0 + tx * 4, bf, bv1);
#pragma unroll
        for (int j = 0; j < 8; j++) As[kc + j][r] = av[j];
        *reinterpret_cast<float4*>(&Bs[kr][tx * 4])      = make_float4(bv0[0], bv0[1], bv0[2], bv0[3]);
        *reinterpret_cast<float4*>(&Bs[kr + 16][tx * 4]) = make_float4(bv1[0], bv1[1], bv1[2], bv1[3]);
        __syncthreads();
#pragma unroll
        for (int k = 0; k < 32; k++) {
            float4 a = *reinterpret_cast<const float4*>(&As[k][ty * 4]);
            float4 b = *reinterpret_cast<const float4*>(&Bs[k][tx * 4]);
            float aa[4] = {a.x, a.y, a.z, a.w}, bb[4] = {b.x, b.y, b.z, b.w};
#pragma unroll
            for (int j = 0; j < 4; j++)
#pragma unroll
                for (int i = 0; i < 4; i++) acc[j][i] += (double)aa[j] * (double)bb[i];
        }
        __syncthreads();
    }
#pragma unroll
    for (int j = 0; j < 4; j++) {
        int m = m0 + ty * 4 + j;
#pragma unroll
        for (int i = 0; i < 4; i++) {
            double v = acc[j][i] * inv_kd[m];
            Cd[(size_t)m * N + n0 + tx * 4 + i] = v;
            Cf[(size_t)m * N + n0 + tx * 4 + i] = (float)v;
        }
    }
}

// ---------------------------------------------------------------------------
// C = [rowscale(A)] @ B^T. BM=BN=64, BK=32, 256 threads, 4x4 micro.
// ---------------------------------------------------------------------------
__global__ __launch_bounds__(256) void gemm_abt(
    const void* __restrict__ A, const void* __restrict__ B,
    const float* __restrict__ As_scale,
    float* __restrict__ C, const void* __restrict__ bias, void* __restrict__ O,
    int M, int N, int K, int amode, int bmode, int epi,
    const int* __restrict__ flagp)
{
    __shared__ float As[32][68];
    __shared__ float Bs[32][68];
    const int flag = *flagp;
    const int abf = amode ? flag : 0;
    const int bbf = bmode ? flag : 0;
    const int t = threadIdx.x;
    const int m0 = blockIdx.y * 64, n0 = blockIdx.x * 64;
    const int r = t & 63, kc = (t >> 6) * 8;
    const int tx = t & 15, ty = t >> 4;
    const float sc = As_scale ? As_scale[m0 + r] : 1.0f;
    float acc[4][4];
#pragma unroll
    for (int j = 0; j < 4; j++)
#pragma unroll
        for (int i = 0; i < 4; i++) acc[j][i] = 0.f;

    for (int k0 = 0; k0 < K; k0 += 32) {
        float av[8], bv[8];
        ld4(A, (size_t)(m0 + r) * K + k0 + kc,     abf, av);
        ld4(A, (size_t)(m0 + r) * K + k0 + kc + 4, abf, av + 4);
        ld4(B, (size_t)(n0 + r) * K + k0 + kc,     bbf, bv);
        ld4(B, (size_t)(n0 + r) * K + k0 + kc + 4, bbf, bv + 4);
#pragma unroll
        for (int j = 0; j < 8; j++) As[kc + j][r] = av[j] * sc;
#pragma unroll
        for (int j = 0; j < 8; j++) Bs[kc + j][r] = bv[j];
        __syncthreads();
#pragma unroll
        for (int k = 0; k < 32; k++) {
            float4 a = *reinterpret_cast<const float4*>(&As[k][ty * 4]);
            float4 b = *reinterpret_cast<const float4*>(&Bs[k][tx * 4]);
            float aa[4] = {a.x, a.y, a.z, a.w}, bb[4] = {b.x, b.y, b.z, b.w};
#pragma unroll
            for (int j = 0; j < 4; j++)
#pragma unroll
                for (int i = 0; i < 4; i++) acc[j][i] += aa[j] * bb[i];
        }
        __syncthreads();
    }
#pragma unroll
    for (int j = 0; j < 4; j++) {
        int m = m0 + ty * 4 + j;
        int n = n0 + tx * 4;
        size_t off = (size_t)m * N + n;
        if (epi == 0) {
            *reinterpret_cast<float4*>(&C[off]) =
                make_float4(acc[j][0], acc[j][1], acc[j][2], acc[j][3]);
        } else {
            float o4[4];
#pragma unroll
            for (int i = 0; i < 4; i++)
                o4[i] = acc[j][i] + (bias ? ldg1(bias, n + i, flag) : 0.f);
            if (flag) {
                ushort4 u = make_ushort4(f2bf(o4[0]), f2bf(o4[1]), f2bf(o4[2]), f2bf(o4[3]));
                *reinterpret_cast<ushort4*>((unsigned short*)O + off) = u;
            } else {
                *reinterpret_cast<float4*>((float*)O + off) =
                    make_float4(o4[0], o4[1], o4[2], o4[3]);
            }
        }
    }
}

// ---------------------------------------------------------------------------
// Top-32 select, one wave per row (4 rows / 256-thread block). No per-lane
// array ever indexed dynamically -> zero scratch spill.
//  1) uint-space bisection for threshold T with count(>=T) in [33,48]
//  2) lane-scan compaction of candidates into LDS (64 slots, -inf padded)
//  3) 64-lane XOR-bitonic shuffle sort by (value desc, index asc)
//  4) margin test rank32 vs rank33; rare fp64 exact rescore of candidates
// ---------------------------------------------------------------------------
__global__ __launch_bounds__(256) void topk_select(
    const float* __restrict__ Sc, const void* __restrict__ X,
    const int* __restrict__ flagp, const double* __restrict__ KW,
    int* __restrict__ idx)
{
    __shared__ float scv[4][64];
    __shared__ int   sci[4][64];
    const int bf = *flagp;
    int w = threadIdx.x >> 6, lane = threadIdx.x & 63;
    int row = blockIdx.x * 4 + w;
    const float* S = Sc + (size_t)row * 1024;

    float v[16]; unsigned int m[16];
#pragma unroll
    for (int j = 0; j < 16; j++) {
        float x = S[j * 64 + lane];
        v[j] = x;
        unsigned int u = __float_as_uint(x);
        m[j] = (u & 0x80000000u) ? ~u : (u | 0x80000000u);
    }
    // bisection: invariant count(>=lo) >= 33, count(>=hi) < 33
    unsigned int lo = 0u, hi = 0xFFFFFFFFu;
    int cnt_lo = 1024;
    for (int it = 0; it < 30; it++) {
        if (cnt_lo <= 48 || hi - lo <= 1) break;
        unsigned int mid = lo + ((hi - lo) >> 1);
        int c = 0;
#pragma unroll
        for (int j = 0; j < 16; j++) c += (m[j] >= mid) ? 1 : 0;
#pragma unroll
        for (int o = 1; o < 64; o <<= 1) c += __shfl_xor(c, o, 64);
        if (c >= 33) { lo = mid; cnt_lo = c; }
        else hi = mid;
    }
    const unsigned int T = lo;
    // per-lane candidate count + exclusive scan across lanes
    int cl = 0;
#pragma unroll
    for (int j = 0; j < 16; j++) cl += (m[j] >= T) ? 1 : 0;
    int inc = cl;
#pragma unroll
    for (int o = 1; o < 64; o <<= 1) {
        int y = __shfl_up(inc, o, 64);
        if (lane >= o) inc += y;
    }
    int pos = inc - cl;
    scv[w][lane] = -INFINITY;
    sci[w][lane] = 0x7FFFFFFF;
    __syncthreads();
#pragma unroll
    for (int j = 0; j < 16; j++) {
        if (m[j] >= T && pos < 64) {
            scv[w][pos] = v[j];
            sci[w][pos] = j * 64 + lane;
            pos++;
        }
    }
    __syncthreads();
    float cv = scv[w][lane];
    int   ci = sci[w][lane];
    // 64-lane bitonic sort, descending by (cv desc, ci asc)
#pragma unroll
    for (int k = 2; k <= 64; k <<= 1) {
#pragma unroll
        for (int jj = k >> 1; jj > 0; jj >>= 1) {
            float ov = __shfl_xor(cv, jj, 64);
            int   oi = __shfl_xor(ci, jj, 64);
            bool up = ((lane & k) == 0);
            bool takemax = (((lane & jj) == 0) == up);
            bool othergreater = (ov > cv) || (ov == cv && oi < ci);
            if (takemax == othergreater) { cv = ov; ci = oi; }
        }
    }
    float v31 = __shfl(cv, 31, 64);   // 32nd largest (fp32)
    float v32 = __shfl(cv, 32, 64);   // 33rd largest (fp32) — real value (cnt>=33)
    if (v31 - v32 > 1e-4f) {
        if (lane < 32) idx[(size_t)row * 32 + lane] = ci;
        return;
    }
    // rare boundary row: exact fp64 rescoring of up to 48 sorted candidates
    float x[5];
#pragma unroll
    for (int j = 0; j < 5; j++) x[j] = ldg1(X, (size_t)row * 320 + lane + 64 * j, bf);
    double eval = -1.0e300; int eidx = 0x7FFFFFFF;
    int myci = (lane < 48) ? ci : 0x7FFFFFFF;
#pragma unroll 1
    for (int c = 0; c < 48; c++) {
        int cidx = __shfl(myci, c, 64);     // wave-uniform broadcast
        if (cidx == 0x7FFFFFFF) continue;   // pad (uniform) -> skip
        const double* kr = KW + (size_t)cidx * 320;
        double s = 0.0;
#pragma unroll
        for (int j = 0; j < 5; j++) s += (double)x[j] * kr[lane + 64 * j];
#pragma unroll
        for (int o = 1; o < 64; o <<= 1) s += __shfl_xor(s, o, 64);
        if (lane == c) { eval = s; eidx = cidx; }
    }
    for (int it = 0; it < 32; it++) {
        double bv = eval; int bi = eidx;
#pragma unroll
        for (int o = 1; o < 64; o <<= 1) {
            double ovd = __shfl_xor(bv, o, 64);
            int    oi  = __shfl_xor(bi, o, 64);
            if (ovd > bv || (ovd == bv && oi < bi)) { bv = ovd; bi = oi; }
        }
        if (lane == 0) idx[(size_t)row * 32 + it] = bi;
        if (eidx == bi) { eval = -1.0e300; eidx = 0x7FFFFFFF; }
    }
}

// ---------------------------------------------------------------------------
// Fused gather + 8-head attention per row. float4 QK, float2 PV.
// ---------------------------------------------------------------------------
__global__ __launch_bounds__(256) void attn_kernel(
    const float* __restrict__ qh, const float* __restrict__ Kp,
    const float* __restrict__ Vp, const int* __restrict__ idx,
    float* __restrict__ ctx)
{
    __shared__ float sq[512];
    __shared__ int   sidx[32];
    __shared__ float sl[8][32];
    __shared__ float sw[8][32];
    int row = blockIdx.x, t = threadIdx.x;
    if (t < 128)
        *reinterpret_cast<float4*>(&sq[t * 4]) =
            *reinterpret_cast<const float4*>(&qh[(size_t)row * 512 + t * 4]);
    if (t < 32) {
        int v = idx[(size_t)row * 32 + t];
        sidx[t] = (v < 0) ? 0 : (v > 1023 ? 1023 : v);
    }
    __syncthreads();

    int h = t >> 5, k = t & 31;
    const float* kp = Kp + (size_t)sidx[k] * 512 + h * 64;
    float acc = 0.f;
#pragma unroll
    for (int d = 0; d < 16; d++) {
        float4 a = *reinterpret_cast<const float4*>(&sq[h * 64 + d * 4]);
        float4 b = *reinterpret_cast<const float4*>(&kp[d * 4]);
        acc += a.x * b.x + a.y * b.y + a.z * b.z + a.w * b.w;
    }
    float logit = acc * 0.125f;
    sl[h][k] = logit;
    __syncthreads();
    float m = -1e30f;
#pragma unroll
    for (int i = 0; i < 32; i++) m = fmaxf(m, sl[h][i]);
    float ssum = 0.f;
#pragma unroll
    for (int i = 0; i < 32; i++) ssum += __expf(sl[h][i] - m);
    sw[h][k] = __expf(logit - m) / ssum;
    __syncthreads();

    int c = t * 2, hh = c >> 6;
    float ax = 0.f, ay = 0.f;
#pragma unroll
    for (int kk = 0; kk < 32; kk++) {
        float2 vv = *reinterpret_cast<const float2*>(&Vp[(size_t)sidx[kk] * 512 + c]);
        float wgt = sw[hh][kk];
        ax += wgt * vv.x; ay += wgt * vv.y;
    }
    *reinterpret_cast<float2*>(&ctx[(size_t)row * 512 + c]) = make_float2(ax, ay);
}

__global__ __launch_bounds__(256) void ln_kernel(
    const float* __restrict__ co, const void* __restrict__ g,
    const void* __restrict__ b, const int* __restrict__ flagp,
    float* __restrict__ o)
{
    __shared__ double ra[256], rb[256];
    int bf = *flagp;
    int r = blockIdx.x, t = threadIdx.x;
    float x0 = co[(size_t)r * 512 + t], x1 = co[(size_t)r * 512 + 256 + t];
    ra[t] = (double)x0 + (double)x1;
    rb[t] = (double)x0 * x0 + (double)x1 * x1;
    __syncthreads();
    for (int s = 128; s > 0; s >>= 1) {
        if (t < s) { ra[t] += ra[t + s]; rb[t] += rb[t + s]; }
        __syncthreads();
    }
    __shared__ float smu, sinv;
    if (t == 0) {
        double mu = ra[0] / 512.0, var = rb[0] / 512.0 - mu * mu;
        smu = (float)mu;
        sinv = (float)(1.0 / sqrt(var + 1e-5));
    }
    __syncthreads();
    o[(size_t)r * 512 + t]       = (x0 - smu) * sinv * ldg1(g, t, bf)       + ldg1(b, t, bf);
    o[(size_t)r * 512 + 256 + t] = (x1 - smu) * sinv * ldg1(g, 256 + t, bf) + ldg1(b, 256 + t, bf);
}

extern "C" void kernel_launch(void* const* d_in, const int* in_sizes, int n_in,
                              void* d_out, int out_size, void* d_ws, size_t ws_size,
                              hipStream_t stream)
{
    const void* X    = d_in[0];
    const void* Wqp  = d_in[1];
    const void* keys = d_in[2];
    const void* vals = d_in[3];
    const void* Wq   = d_in[4];
    const void* Wk   = d_in[5];
    const void* Wv   = d_in[6];
    const void* Wo   = d_in[7];
    const void* ln_g = d_in[8];
    const void* ln_b = d_in[9];
    const void* Wout = d_in[10];
    const void* bout = d_in[11];

    // ---- workspace (float units; ~23.0 MiB) ----
    float* ws = (float*)d_ws;
    float*  Sc     = ws;                       // 4096x1024 fp32 = 4,194,304 fl
    float*  Xreg   = ws;                       // 2,097,152: qh -> co (after topk)
    float*  Yreg   = ws + 2097152;             // 2,097,152: ctx -> normed
    float*  Mf     = ws + 4194304;             // 163,840 fl (Kp region; dead pre-Kp)
    float*  Kp     = ws + 4194304;             // 524,288
    float*  KWf    = ws + 4718592;             // 327,680 fl (Vp region; dead pre-Vp)
    float*  Vp     = ws + 4718592;             // 524,288
    double* KW     = (double*)(ws + 5242880);  // 1024*320 dbl (655,360 fl)
    int*    idx    = (int*)(ws + 5898240);     // 131,072
    double* inv_kd = (double*)(ws + 6029312);  // 2,048 fl
    float*  inv_kf = ws + 6031360;
    float*  inv_vf = ws + 6032384;
    int*    flag   = (int*)(ws + 6033408);
    float*  qh     = Xreg;
    float*  co     = Xreg;                     // qh dead after attn
    float*  ctx    = Yreg;
    float*  normed = Yreg;                     // ctx dead after Wo-gemm

    detect_kernel<<<1, 64, 0, stream>>>(ln_g, flag);
    norms_kernel<<<2048, 256, 0, stream>>>(keys, vals, flag, inv_kd, inv_kf, inv_vf);
    // KW (fp64) + KWf (fp32) = rowscale(keys) @ Wqp
    gemm_ab_f64<<<dim3(5, 16), 256, 0, stream>>>(
        keys, Wqp, flag, inv_kd, KW, KWf, 1024, 320, 512);
    // Mf = Wq @ Wqp (fp32)
    gemm_ab<<<dim3(5, 8), 256, 0, stream>>>(Wq, Wqp, flag, Mf, 512, 320, 512);
    // Sc = X @ KWf^T (fp32 bulk), single full-GPU launch
    gemm_abt<<<dim3(16, 64), 256, 0, stream>>>(
        X, KWf, nullptr, Sc, nullptr, nullptr, 4096, 1024, 320, 1, 0, 0, flag);
    // top-32 select (+ rare fp64 boundary refine) -> exact top-32 set
    topk_select<<<1024, 256, 0, stream>>>(Sc, X, flag, KW, idx);
    // qh = X @ Mf^T (overwrites Sc lower half — Sc dead)
    gemm_abt<<<dim3(8, 64), 256, 0, stream>>>(
        X, Mf, nullptr, qh, nullptr, nullptr, 4096, 512, 320, 1, 0, 0, flag);
    // Kp/Vp = rowscale(keys|vals) @ Wk^T|Wv^T (overwrite Mf / KWf — dead)
    gemm_abt<<<dim3(8, 16), 256, 0, stream>>>(
        keys, Wk, inv_kf, Kp, nullptr, nullptr, 1024, 512, 512, 1, 1, 0, flag);
    gemm_abt<<<dim3(8, 16), 256, 0, stream>>>(
        vals, Wv, inv_vf, Vp, nullptr, nullptr, 1024, 512, 512, 1, 1, 0, flag);
    attn_kernel<<<4096, 256, 0, stream>>>(qh, Kp, Vp, idx, ctx);
    gemm_abt<<<dim3(8, 64), 256, 0, stream>>>(
        ctx, Wo, nullptr, co, nullptr, nullptr, 4096, 512, 512, 0, 1, 0, flag);
    ln_kernel<<<4096, 256, 0, stream>>>(co, ln_g, ln_b, flag, normed);
    gemm_abt<<<dim3(5, 64), 256, 0, stream>>>(
        normed, Wout, nullptr, nullptr, bout, d_out, 4096, 320, 512, 0, 1, 1, flag);
}

// Round 7
// 474.157 us; speedup vs baseline: 2.7088x; 1.0141x over previous
//
#include <hip/hip_runtime.h>

// GatedLTMMemory: 4096 rows, QD=320, D=512, S=1024, H=8, K=32, DH=64
// Runtime dtype detect (fp32 vs bf16) via ln_g==ones. (Resolved: fp32.)
//
// Algebra:
//   scores = X @ KW^T,  KW[s,:] = (1/||keys_s||)*(keys_s @ Wqp)
//     bulk in fp32 (KWf); top-[33,48] candidates via uint-bisection over LDS keys;
//     rows with rank32/33 gap < 1e-4 re-scored exactly in fp64 (KW) -> exact set.
//   qh = X @ Mf^T,  Mf = Wq @ Wqp          (fp32)
//   Kp = rowscale(keys) @ Wk^T, Vp likewise (fp32, gathered in attn)

__device__ __forceinline__ float bf2f(unsigned short u) {
    return __uint_as_float(((unsigned int)u) << 16);
}
__device__ __forceinline__ unsigned short f2bf(float f) {
    unsigned int u = __float_as_uint(f);
    u += 0x7FFFu + ((u >> 16) & 1u);
    return (unsigned short)(u >> 16);
}
__device__ __forceinline__ float ldg1(const void* p, size_t i, int bf) {
    return bf ? bf2f(((const unsigned short*)p)[i]) : ((const float*)p)[i];
}
__device__ __forceinline__ void ld4(const void* p, size_t i, int bf, float* o) {
    if (bf) {
        ushort4 v = *reinterpret_cast<const ushort4*>((const unsigned short*)p + i);
        o[0] = bf2f(v.x); o[1] = bf2f(v.y); o[2] = bf2f(v.z); o[3] = bf2f(v.w);
    } else {
        float4 v = *reinterpret_cast<const float4*>((const float*)p + i);
        o[0] = v.x; o[1] = v.y; o[2] = v.z; o[3] = v.w;
    }
}
// order-preserving float->uint key and inverse
__device__ __forceinline__ unsigned int fkey(float x) {
    unsigned int u = __float_as_uint(x);
    return (u & 0x80000000u) ? ~u : (u | 0x80000000u);
}
__device__ __forceinline__ float funkey(unsigned int k) {
    unsigned int u = (k & 0x80000000u) ? (k & 0x7FFFFFFFu) : ~k;
    return __uint_as_float(u);
}

__global__ void detect_kernel(const void* __restrict__ g, int* __restrict__ flag)
{
    if (threadIdx.x == 0) {
        unsigned int w = *(const unsigned int*)g;
        *flag = ((w & 0xFFFFu) != 0u) ? 1 : 0;
    }
}

__global__ __launch_bounds__(256) void norms_kernel(
    const void* __restrict__ keys, const void* __restrict__ vals,
    const int* __restrict__ flagp,
    double* __restrict__ inv_kd, float* __restrict__ inv_kf, float* __restrict__ inv_vf)
{
    __shared__ double red[256];
    int bf = *flagp;
    int r = blockIdx.x, t = threadIdx.x;
    const void* src = (r < 1024) ? keys : vals;
    size_t base = (size_t)((r < 1024) ? r : r - 1024) * 512;
    float x0 = ldg1(src, base + t, bf), x1 = ldg1(src, base + t + 256, bf);
    red[t] = (double)x0 * x0 + (double)x1 * x1;
    __syncthreads();
    for (int s = 128; s > 0; s >>= 1) {
        if (t < s) red[t] += red[t + s];
        __syncthreads();
    }
    if (t == 0) {
        double rs = 1.0 / sqrt(red[0] + 1e-12);
        if (r < 1024) { inv_kd[r] = rs; inv_kf[r] = (float)rs; }
        else          { inv_vf[r - 1024] = (float)rs; }
    }
}

// ---------------------------------------------------------------------------
// C = A @ B (B row-major [K,N]) fp32. BM=BN=64, BK=32, 256 threads, 4x4 micro.
// ---------------------------------------------------------------------------
__global__ __launch_bounds__(256) void gemm_ab(
    const void* __restrict__ A, const void* __restrict__ B,
    const int* __restrict__ flagp, float* __restrict__ Cf, int M, int N, int K)
{
    __shared__ float As[32][68];
    __shared__ float Bs[32][68];
    const int bf = *flagp;
    const int t = threadIdx.x;
    const int m0 = blockIdx.y * 64, n0 = blockIdx.x * 64;
    const int r = t & 63, kc = (t >> 6) * 8;
    const int tx = t & 15, kr = t >> 4;
    const int ty = t >> 4;
    float acc[4][4];
#pragma unroll
    for (int j = 0; j < 4; j++)
#pragma unroll
        for (int i = 0; i < 4; i++) acc[j][i] = 0.f;

    for (int k0 = 0; k0 < K; k0 += 32) {
        float av[8], bv0[4], bv1[4];
        ld4(A, (size_t)(m0 + r) * K + k0 + kc,     bf, av);
        ld4(A, (size_t)(m0 + r) * K + k0 + kc + 4, bf, av + 4);
        ld4(B, (size_t)(k0 + kr) * N + n0 + tx * 4,      bf, bv0);
        ld4(B, (size_t)(k0 + kr + 16) * N + n0 + tx * 4, bf, bv1);
#pragma unroll
        for (int j = 0; j < 8; j++) As[kc + j][r] = av[j];
        *reinterpret_cast<float4*>(&Bs[kr][tx * 4])      = make_float4(bv0[0], bv0[1], bv0[2], bv0[3]);
        *reinterpret_cast<float4*>(&Bs[kr + 16][tx * 4]) = make_float4(bv1[0], bv1[1], bv1[2], bv1[3]);
        __syncthreads();
#pragma unroll
        for (int k = 0; k < 32; k++) {
            float4 a = *reinterpret_cast<const float4*>(&As[k][ty * 4]);
            float4 b = *reinterpret_cast<const float4*>(&Bs[k][tx * 4]);
            float aa[4] = {a.x, a.y, a.z, a.w}, bb[4] = {b.x, b.y, b.z, b.w};
#pragma unroll
            for (int j = 0; j < 4; j++)
#pragma unroll
                for (int i = 0; i < 4; i++) acc[j][i] += aa[j] * bb[i];
        }
        __syncthreads();
    }
#pragma unroll
    for (int j = 0; j < 4; j++) {
        int m = m0 + ty * 4 + j;
#pragma unroll
        for (int i = 0; i < 4; i++)
            Cf[(size_t)m * N + n0 + tx * 4 + i] = acc[j][i];
    }
}

// KW = rowscale(keys) @ Wqp, fp64 accumulate; writes fp64 KW and fp32 KWf.
__global__ __launch_bounds__(256) void gemm_ab_f64(
    const void* __restrict__ A, const void* __restrict__ B,
    const int* __restrict__ flagp, const double* __restrict__ inv_kd,
    double* __restrict__ Cd, float* __restrict__ Cf, int M, int N, int K)
{
    __shared__ float As[32][68];
    __shared__ float Bs[32][68];
    const int bf = *flagp;
    const int t = threadIdx.x;
    const int m0 = blockIdx.y * 64, n0 = blockIdx.x * 64;
    const int r = t & 63, kc = (t >> 6) * 8;
    const int tx = t & 15, kr = t >> 4;
    const int ty = t >> 4;
    double acc[4][4];
#pragma unroll
    for (int j = 0; j < 4; j++)
#pragma unroll
        for (int i = 0; i < 4; i++) acc[j][i] = 0.0;

    for (int k0 = 0; k0 < K; k0 += 32) {
        float av[8], bv0[4], bv1[4];
        ld4(A, (size_t)(m0 + r) * K + k0 + kc,     bf, av);
        ld4(A, (size_t)(m0 + r) * K + k0 + kc + 4, bf, av + 4);
        ld4(B, (size_t)(k0 + kr) * N + n0 + tx * 4,      bf, bv0);
        ld4(B, (size_t)(k0 + kr + 16) * N + n0 + tx * 4, bf, bv1);
#pragma unroll
        for (int j = 0; j < 8; j++) As[kc + j][r] = av[j];
        *reinterpret_cast<float4*>(&Bs[kr][tx * 4])      = make_float4(bv0[0], bv0[1], bv0[2], bv0[3]);
        *reinterpret_cast<float4*>(&Bs[kr + 16][tx * 4]) = make_float4(bv1[0], bv1[1], bv1[2], bv1[3]);
        __syncthreads();
#pragma unroll
        for (int k = 0; k < 32; k++) {
            float4 a = *reinterpret_cast<const float4*>(&As[k][ty * 4]);
            float4 b = *reinterpret_cast<const float4*>(&Bs[k][tx * 4]);
            float aa[4] = {a.x, a.y, a.z, a.w}, bb[4] = {b.x, b.y, b.z, b.w};
#pragma unroll
            for (int j = 0; j < 4; j++)
#pragma unroll
                for (int i = 0; i < 4; i++) acc[j][i] += (double)aa[j] * (double)bb[i];
        }
        __syncthreads();
    }
#pragma unroll
    for (int j = 0; j < 4; j++) {
        int m = m0 + ty * 4 + j;
#pragma unroll
        for (int i = 0; i < 4; i++) {
            double v = acc[j][i] * inv_kd[m];
            Cd[(size_t)m * N + n0 + tx * 4 + i] = v;
            Cf[(size_t)m * N + n0 + tx * 4 + i] = (float)v;
        }
    }
}

// ---------------------------------------------------------------------------
// C = [rowscale(A)] @ B^T. BM=BN=64, BK=32, 256 threads, 4x4 micro.
// ---------------------------------------------------------------------------
__global__ __launch_bounds__(256) void gemm_abt(
    const void* __restrict__ A, const void* __restrict__ B,
    const float* __restrict__ As_scale,
    float* __restrict__ C, const void* __restrict__ bias, void* __restrict__ O,
    int M, int N, int K, int amode, int bmode, int epi,
    const int* __restrict__ flagp)
{
    __shared__ float As[32][68];
    __shared__ float Bs[32][68];
    const int flag = *flagp;
    const int abf = amode ? flag : 0;
    const int bbf = bmode ? flag : 0;
    const int t = threadIdx.x;
    const int m0 = blockIdx.y * 64, n0 = blockIdx.x * 64;
    const int r = t & 63, kc = (t >> 6) * 8;
    const int tx = t & 15, ty = t >> 4;
    const float sc = As_scale ? As_scale[m0 + r] : 1.0f;
    float acc[4][4];
#pragma unroll
    for (int j = 0; j < 4; j++)
#pragma unroll
        for (int i = 0; i < 4; i++) acc[j][i] = 0.f;

    for (int k0 = 0; k0 < K; k0 += 32) {
        float av[8], bv[8];
        ld4(A, (size_t)(m0 + r) * K + k0 + kc,     abf, av);
        ld4(A, (size_t)(m0 + r) * K + k0 + kc + 4, abf, av + 4);
        ld4(B, (size_t)(n0 + r) * K + k0 + kc,     bbf, bv);
        ld4(B, (size_t)(n0 + r) * K + k0 + kc + 4, bbf, bv + 4);
#pragma unroll
        for (int j = 0; j < 8; j++) As[kc + j][r] = av[j] * sc;
#pragma unroll
        for (int j = 0; j < 8; j++) Bs[kc + j][r] = bv[j];
        __syncthreads();
#pragma unroll
        for (int k = 0; k < 32; k++) {
            float4 a = *reinterpret_cast<const float4*>(&As[k][ty * 4]);
            float4 b = *reinterpret_cast<const float4*>(&Bs[k][tx * 4]);
            float aa[4] = {a.x, a.y, a.z, a.w}, bb[4] = {b.x, b.y, b.z, b.w};
#pragma unroll
            for (int j = 0; j < 4; j++)
#pragma unroll
                for (int i = 0; i < 4; i++) acc[j][i] += aa[j] * bb[i];
        }
        __syncthreads();
    }
#pragma unroll
    for (int j = 0; j < 4; j++) {
        int m = m0 + ty * 4 + j;
        int n = n0 + tx * 4;
        size_t off = (size_t)m * N + n;
        if (epi == 0) {
            *reinterpret_cast<float4*>(&C[off]) =
                make_float4(acc[j][0], acc[j][1], acc[j][2], acc[j][3]);
        } else {
            float o4[4];
#pragma unroll
            for (int i = 0; i < 4; i++)
                o4[i] = acc[j][i] + (bias ? ldg1(bias, n + i, flag) : 0.f);
            if (flag) {
                ushort4 u = make_ushort4(f2bf(o4[0]), f2bf(o4[1]), f2bf(o4[2]), f2bf(o4[3]));
                *reinterpret_cast<ushort4*>((unsigned short*)O + off) = u;
            } else {
                *reinterpret_cast<float4*>((float*)O + off) =
                    make_float4(o4[0], o4[1], o4[2], o4[3]);
            }
        }
    }
}

// ---------------------------------------------------------------------------
// Top-32 select, one wave per row (4 rows / 256-thread block).
// ZERO per-lane arrays (scratch-spill proof): row lives in LDS as monotone
// uint keys; bisection for threshold with count in [33,48]; compaction into a
// 64-slot LDS buffer; 64-lane shuffle bitonic sort; margin test; rare fp64
// exact rescore (scalars only).
// ---------------------------------------------------------------------------
__global__ __launch_bounds__(256) void topk_select(
    const float* __restrict__ Sc, const void* __restrict__ X,
    const int* __restrict__ flagp, const double* __restrict__ KW,
    int* __restrict__ idx)
{
    __shared__ unsigned int srow[4][1024];
    __shared__ unsigned int scv[4][64];
    __shared__ int          sci[4][64];
    const int bf = *flagp;
    const int w = threadIdx.x >> 6, lane = threadIdx.x & 63;
    const int row = blockIdx.x * 4 + w;
    const float* S = Sc + (size_t)row * 1024;

    // stage monotone keys into LDS (float4 in, uint4 out; col = lane*4 + q*256 + e)
#pragma unroll
    for (int q = 0; q < 4; q++) {
        float4 v = *reinterpret_cast<const float4*>(&S[lane * 4 + q * 256]);
        uint4 k = make_uint4(fkey(v.x), fkey(v.y), fkey(v.z), fkey(v.w));
        *reinterpret_cast<uint4*>(&srow[w][lane * 4 + q * 256]) = k;
    }
    scv[w][lane] = 0u;
    sci[w][lane] = 0x7FFFFFFF;
    __syncthreads();

    // bisection: invariant count(>=lo) >= 33 (lo=0 trivially), count(>=hi) < 33
    unsigned int lo = 0u, hi = 0xFFFFFFFFu;
    int cnt_lo = 1024;
    while (cnt_lo > 48 && hi - lo > 1u) {
        unsigned int mid = lo + ((hi - lo) >> 1);
        int c = 0;
#pragma unroll
        for (int q = 0; q < 4; q++) {
            uint4 k = *reinterpret_cast<const uint4*>(&srow[w][lane * 4 + q * 256]);
            c += (k.x >= mid) + (k.y >= mid) + (k.z >= mid) + (k.w >= mid);
        }
#pragma unroll
        for (int o = 1; o < 64; o <<= 1) c += __shfl_xor(c, o, 64);
        if (c >= 33) { lo = mid; cnt_lo = c; }
        else hi = mid;
    }
    const unsigned int T = lo;

    // per-lane candidate count + exclusive lane scan
    int cl = 0;
#pragma unroll
    for (int q = 0; q < 4; q++) {
        uint4 k = *reinterpret_cast<const uint4*>(&srow[w][lane * 4 + q * 256]);
        cl += (k.x >= T) + (k.y >= T) + (k.z >= T) + (k.w >= T);
    }
    int inc = cl;
#pragma unroll
    for (int o = 1; o < 64; o <<= 1) {
        int y = __shfl_up(inc, o, 64);
        if (lane >= o) inc += y;
    }
    int pos = inc - cl;
#pragma unroll
    for (int q = 0; q < 4; q++) {
        uint4 k = *reinterpret_cast<const uint4*>(&srow[w][lane * 4 + q * 256]);
        int base = lane * 4 + q * 256;
        if (k.x >= T && pos < 64) { scv[w][pos] = k.x; sci[w][pos] = base + 0; pos++; }
        if (k.y >= T && pos < 64) { scv[w][pos] = k.y; sci[w][pos] = base + 1; pos++; }
        if (k.z >= T && pos < 64) { scv[w][pos] = k.z; sci[w][pos] = base + 2; pos++; }
        if (k.w >= T && pos < 64) { scv[w][pos] = k.w; sci[w][pos] = base + 3; pos++; }
    }
    __syncthreads();
    unsigned int cv = scv[w][lane];
    int          ci = sci[w][lane];
    // 64-lane bitonic sort, descending by (key desc, idx asc)
#pragma unroll
    for (int k = 2; k <= 64; k <<= 1) {
#pragma unroll
        for (int jj = k >> 1; jj > 0; jj >>= 1) {
            unsigned int ov = __shfl_xor(cv, jj, 64);
            int          oi = __shfl_xor(ci, jj, 64);
            bool up = ((lane & k) == 0);
            bool takemax = (((lane & jj) == 0) == up);
            bool othergreater = (ov > cv) || (ov == cv && oi < ci);
            if (takemax == othergreater) { cv = ov; ci = oi; }
        }
    }
    float v31 = funkey(__shfl(cv, 31, 64));   // 32nd largest
    float v32 = funkey(__shfl(cv, 32, 64));   // 33rd largest (cnt>=33 guarantees real)
    if (v31 - v32 > 1e-4f) {
        if (lane < 32) idx[(size_t)row * 32 + lane] = ci;
        return;
    }
    // rare boundary row: exact fp64 rescoring of up to 48 sorted candidates
    size_t xb = (size_t)row * 320;
    float x0 = ldg1(X, xb + lane,       bf);
    float x1 = ldg1(X, xb + lane + 64,  bf);
    float x2 = ldg1(X, xb + lane + 128, bf);
    float x3 = ldg1(X, xb + lane + 192, bf);
    float x4 = ldg1(X, xb + lane + 256, bf);
    double eval = -1.0e300; int eidx = 0x7FFFFFFF;
    int myci = (lane < 48) ? ci : 0x7FFFFFFF;
#pragma unroll 1
    for (int c = 0; c < 48; c++) {
        int cidx = __shfl(myci, c, 64);     // wave-uniform broadcast
        if (cidx == 0x7FFFFFFF) continue;   // pad slot (uniform) -> skip
        const double* kr = KW + (size_t)cidx * 320;
        double s = (double)x0 * kr[lane]
                 + (double)x1 * kr[lane + 64]
                 + (double)x2 * kr[lane + 128]
                 + (double)x3 * kr[lane + 192]
                 + (double)x4 * kr[lane + 256];
#pragma unroll
        for (int o = 1; o < 64; o <<= 1) s += __shfl_xor(s, o, 64);
        if (lane == c) { eval = s; eidx = cidx; }
    }
    for (int it = 0; it < 32; it++) {
        double bv = eval; int bi = eidx;
#pragma unroll
        for (int o = 1; o < 64; o <<= 1) {
            double ovd = __shfl_xor(bv, o, 64);
            int    oi  = __shfl_xor(bi, o, 64);
            if (ovd > bv || (ovd == bv && oi < bi)) { bv = ovd; bi = oi; }
        }
        if (lane == 0) idx[(size_t)row * 32 + it] = bi;
        if (eidx == bi) { eval = -1.0e300; eidx = 0x7FFFFFFF; }
    }
}

// ---------------------------------------------------------------------------
// Fused gather + 8-head attention per row. float4 QK, float2 PV.
// ---------------------------------------------------------------------------
__global__ __launch_bounds__(256) void attn_kernel(
    const float* __restrict__ qh, const float* __restrict__ Kp,
    const float* __restrict__ Vp, const int* __restrict__ idx,
    float* __restrict__ ctx)
{
    __shared__ float sq[512];
    __shared__ int   sidx[32];
    __shared__ float sl[8][32];
    __shared__ float sw[8][32];
    int row = blockIdx.x, t = threadIdx.x;
    if (t < 128)
        *reinterpret_cast<float4*>(&sq[t * 4]) =
            *reinterpret_cast<const float4*>(&qh[(size_t)row * 512 + t * 4]);
    if (t < 32) {
        int v = idx[(size_t)row * 32 + t];
        sidx[t] = (v < 0) ? 0 : (v > 1023 ? 1023 : v);
    }
    __syncthreads();

    int h = t >> 5, k = t & 31;
    const float* kp = Kp + (size_t)sidx[k] * 512 + h * 64;
    float acc = 0.f;
#pragma unroll
    for (int d = 0; d < 16; d++) {
        float4 a = *reinterpret_cast<const float4*>(&sq[h * 64 + d * 4]);
        float4 b = *reinterpret_cast<const float4*>(&kp[d * 4]);
        acc += a.x * b.x + a.y * b.y + a.z * b.z + a.w * b.w;
    }
    float logit = acc * 0.125f;
    sl[h][k] = logit;
    __syncthreads();
    float m = -1e30f;
#pragma unroll
    for (int i = 0; i < 32; i++) m = fmaxf(m, sl[h][i]);
    float ssum = 0.f;
#pragma unroll
    for (int i = 0; i < 32; i++) ssum += __expf(sl[h][i] - m);
    sw[h][k] = __expf(logit - m) / ssum;
    __syncthreads();

    int c = t * 2, hh = c >> 6;
    float ax = 0.f, ay = 0.f;
#pragma unroll
    for (int kk = 0; kk < 32; kk++) {
        float2 vv = *reinterpret_cast<const float2*>(&Vp[(size_t)sidx[kk] * 512 + c]);
        float wgt = sw[hh][kk];
        ax += wgt * vv.x; ay += wgt * vv.y;
    }
    *reinterpret_cast<float2*>(&ctx[(size_t)row * 512 + c]) = make_float2(ax, ay);
}

__global__ __launch_bounds__(256) void ln_kernel(
    const float* __restrict__ co, const void* __restrict__ g,
    const void* __restrict__ b, const int* __restrict__ flagp,
    float* __restrict__ o)
{
    __shared__ double ra[256], rb[256];
    int bf = *flagp;
    int r = blockIdx.x, t = threadIdx.x;
    float x0 = co[(size_t)r * 512 + t], x1 = co[(size_t)r * 512 + 256 + t];
    ra[t] = (double)x0 + (double)x1;
    rb[t] = (double)x0 * x0 + (double)x1 * x1;
    __syncthreads();
    for (int s = 128; s > 0; s >>= 1) {
        if (t < s) { ra[t] += ra[t + s]; rb[t] += rb[t + s]; }
        __syncthreads();
    }
    __shared__ float smu, sinv;
    if (t == 0) {
        double mu = ra[0] / 512.0, var = rb[0] / 512.0 - mu * mu;
        smu = (float)mu;
        sinv = (float)(1.0 / sqrt(var + 1e-5));
    }
    __syncthreads();
    o[(size_t)r * 512 + t]       = (x0 - smu) * sinv * ldg1(g, t, bf)       + ldg1(b, t, bf);
    o[(size_t)r * 512 + 256 + t] = (x1 - smu) * sinv * ldg1(g, 256 + t, bf) + ldg1(b, 256 + t, bf);
}

extern "C" void kernel_launch(void* const* d_in, const int* in_sizes, int n_in,
                              void* d_out, int out_size, void* d_ws, size_t ws_size,
                              hipStream_t stream)
{
    const void* X    = d_in[0];
    const void* Wqp  = d_in[1];
    const void* keys = d_in[2];
    const void* vals = d_in[3];
    const void* Wq   = d_in[4];
    const void* Wk   = d_in[5];
    const void* Wv   = d_in[6];
    const void* Wo   = d_in[7];
    const void* ln_g = d_in[8];
    const void* ln_b = d_in[9];
    const void* Wout = d_in[10];
    const void* bout = d_in[11];

    // ---- workspace (float units; ~23.0 MiB) ----
    float* ws = (float*)d_ws;
    float*  Sc     = ws;                       // 4096x1024 fp32 = 4,194,304 fl
    float*  Xreg   = ws;                       // 2,097,152: qh -> co (after topk)
    float*  Yreg   = ws + 2097152;             // 2,097,152: ctx -> normed
    float*  Mf     = ws + 4194304;             // 163,840 fl (Kp region; dead pre-Kp)
    float*  Kp     = ws + 4194304;             // 524,288
    float*  KWf    = ws + 4718592;             // 327,680 fl (Vp region; dead pre-Vp)
    float*  Vp     = ws + 4718592;             // 524,288
    double* KW     = (double*)(ws + 5242880);  // 1024*320 dbl (655,360 fl)
    int*    idx    = (int*)(ws + 5898240);     // 131,072
    double* inv_kd = (double*)(ws + 6029312);  // 2,048 fl
    float*  inv_kf = ws + 6031360;
    float*  inv_vf = ws + 6032384;
    int*    flag   = (int*)(ws + 6033408);
    float*  qh     = Xreg;
    float*  co     = Xreg;                     // qh dead after attn
    float*  ctx    = Yreg;
    float*  normed = Yreg;                     // ctx dead after Wo-gemm

    detect_kernel<<<1, 64, 0, stream>>>(ln_g, flag);
    norms_kernel<<<2048, 256, 0, stream>>>(keys, vals, flag, inv_kd, inv_kf, inv_vf);
    // KW (fp64) + KWf (fp32) = rowscale(keys) @ Wqp
    gemm_ab_f64<<<dim3(5, 16), 256, 0, stream>>>(
        keys, Wqp, flag, inv_kd, KW, KWf, 1024, 320, 512);
    // Mf = Wq @ Wqp (fp32)
    gemm_ab<<<dim3(5, 8), 256, 0, stream>>>(Wq, Wqp, flag, Mf, 512, 320, 512);
    // Sc = X @ KWf^T (fp32 bulk), single full-GPU launch
    gemm_abt<<<dim3(16, 64), 256, 0, stream>>>(
        X, KWf, nullptr, Sc, nullptr, nullptr, 4096, 1024, 320, 1, 0, 0, flag);
    // top-32 select (+ rare fp64 boundary refine) -> exact top-32 set
    topk_select<<<1024, 256, 0, stream>>>(Sc, X, flag, KW, idx);
    // qh = X @ Mf^T (overwrites Sc lower half — Sc dead)
    gemm_abt<<<dim3(8, 64), 256, 0, stream>>>(
        X, Mf, nullptr, qh, nullptr, nullptr, 4096, 512, 320, 1, 0, 0, flag);
    // Kp/Vp = rowscale(keys|vals) @ Wk^T|Wv^T (overwrite Mf / KWf — dead)
    gemm_abt<<<dim3(8, 16), 256, 0, stream>>>(
        keys, Wk, inv_kf, Kp, nullptr, nullptr, 1024, 512, 512, 1, 1, 0, flag);
    gemm_abt<<<dim3(8, 16), 256, 0, stream>>>(
        vals, Wv, inv_vf, Vp, nullptr, nullptr, 1024, 512, 512, 1, 1, 0, flag);
    attn_kernel<<<4096, 256, 0, stream>>>(qh, Kp, Vp, idx, ctx);
    gemm_abt<<<dim3(8, 64), 256, 0, stream>>>(
        ctx, Wo, nullptr, co, nullptr, nullptr, 4096, 512, 512, 0, 1, 0, flag);
    ln_kernel<<<4096, 256, 0, stream>>>(co, ln_g, ln_b, flag, normed);
    gemm_abt<<<dim3(5, 64), 256, 0, stream>>>(
        normed, Wout, nullptr, nullptr, bout, d_out, 4096, 320, 512, 0, 1, 1, flag);
}

// Round 8
// 429.149 us; speedup vs baseline: 2.9929x; 1.1049x over previous
//
#include <hip/hip_runtime.h>

// GatedLTMMemory: 4096 rows, QD=320, D=512, S=1024, H=8, K=32, DH=64
// Dtype (fp32 vs bf16) derived inline in every kernel from ln_g[0] (== 1.0).
//
// Algebra:
//   scores = X @ KW^T,  KW[s,:] = (1/||keys_s||)*(keys_s @ Wqp)
//     bulk fp32 (KWf); top-[33,48] candidates via uint-bisection over LDS keys;
//     rows with rank32/33 gap < 1e-4 re-scored exactly in fp64 (KW), lane-parallel.
//   qh = X @ Mf^T,  Mf = Wq @ Wqp          (fp32)
//   Kp = rowscale(keys) @ Wk^T, Vp likewise (fp32, gathered in attn; one launch)
//   LayerNorm fused into output GEMM via per-row (mu, 1/sigma) stats.

__device__ __forceinline__ float bf2f(unsigned short u) {
    return __uint_as_float(((unsigned int)u) << 16);
}
__device__ __forceinline__ unsigned short f2bf(float f) {
    unsigned int u = __float_as_uint(f);
    u += 0x7FFFu + ((u >> 16) & 1u);
    return (unsigned short)(u >> 16);
}
__device__ __forceinline__ int detect_bf(const void* g) {
    return ((*(const unsigned int*)g) & 0xFFFFu) != 0u;   // fp32 1.0f low16==0
}
__device__ __forceinline__ float ldg1(const void* p, size_t i, int bf) {
    return bf ? bf2f(((const unsigned short*)p)[i]) : ((const float*)p)[i];
}
__device__ __forceinline__ void ld4(const void* p, size_t i, int bf, float* o) {
    if (bf) {
        ushort4 v = *reinterpret_cast<const ushort4*>((const unsigned short*)p + i);
        o[0] = bf2f(v.x); o[1] = bf2f(v.y); o[2] = bf2f(v.z); o[3] = bf2f(v.w);
    } else {
        float4 v = *reinterpret_cast<const float4*>((const float*)p + i);
        o[0] = v.x; o[1] = v.y; o[2] = v.z; o[3] = v.w;
    }
}
__device__ __forceinline__ unsigned int fkey(float x) {
    unsigned int u = __float_as_uint(x);
    return (u & 0x80000000u) ? ~u : (u | 0x80000000u);
}
__device__ __forceinline__ float funkey(unsigned int k) {
    unsigned int u = (k & 0x80000000u) ? (k & 0x7FFFFFFFu) : ~k;
    return __uint_as_float(u);
}

__global__ __launch_bounds__(256) void norms_kernel(
    const void* __restrict__ keys, const void* __restrict__ vals,
    const void* __restrict__ gdet,
    double* __restrict__ inv_kd, float* __restrict__ inv_kf, float* __restrict__ inv_vf)
{
    __shared__ double red[256];
    int bf = detect_bf(gdet);
    int r = blockIdx.x, t = threadIdx.x;
    const void* src = (r < 1024) ? keys : vals;
    size_t base = (size_t)((r < 1024) ? r : r - 1024) * 512;
    float x0 = ldg1(src, base + t, bf), x1 = ldg1(src, base + t + 256, bf);
    red[t] = (double)x0 * x0 + (double)x1 * x1;
    __syncthreads();
    for (int s = 128; s > 0; s >>= 1) {
        if (t < s) red[t] += red[t + s];
        __syncthreads();
    }
    if (t == 0) {
        double rs = 1.0 / sqrt(red[0] + 1e-12);
        if (r < 1024) { inv_kd[r] = rs; inv_kf[r] = (float)rs; }
        else          { inv_vf[r - 1024] = (float)rs; }
    }
}

// ---------------------------------------------------------------------------
// C = A @ B (B row-major [K,N]) fp32. BM=BN=64, BK=32, 256 threads, 4x4 micro.
// ---------------------------------------------------------------------------
__global__ __launch_bounds__(256) void gemm_ab(
    const void* __restrict__ A, const void* __restrict__ B,
    const void* __restrict__ gdet, float* __restrict__ Cf, int M, int N, int K)
{
    __shared__ float As[32][68];
    __shared__ float Bs[32][68];
    const int bf = detect_bf(gdet);
    const int t = threadIdx.x;
    const int m0 = blockIdx.y * 64, n0 = blockIdx.x * 64;
    const int r = t & 63, kc = (t >> 6) * 8;
    const int tx = t & 15, kr = t >> 4;
    const int ty = t >> 4;
    float acc[4][4];
#pragma unroll
    for (int j = 0; j < 4; j++)
#pragma unroll
        for (int i = 0; i < 4; i++) acc[j][i] = 0.f;

    for (int k0 = 0; k0 < K; k0 += 32) {
        float av[8], bv0[4], bv1[4];
        ld4(A, (size_t)(m0 + r) * K + k0 + kc,     bf, av);
        ld4(A, (size_t)(m0 + r) * K + k0 + kc + 4, bf, av + 4);
        ld4(B, (size_t)(k0 + kr) * N + n0 + tx * 4,      bf, bv0);
        ld4(B, (size_t)(k0 + kr + 16) * N + n0 + tx * 4, bf, bv1);
#pragma unroll
        for (int j = 0; j < 8; j++) As[kc + j][r] = av[j];
        *reinterpret_cast<float4*>(&Bs[kr][tx * 4])      = make_float4(bv0[0], bv0[1], bv0[2], bv0[3]);
        *reinterpret_cast<float4*>(&Bs[kr + 16][tx * 4]) = make_float4(bv1[0], bv1[1], bv1[2], bv1[3]);
        __syncthreads();
#pragma unroll
        for (int k = 0; k < 32; k++) {
            float4 a = *reinterpret_cast<const float4*>(&As[k][ty * 4]);
            float4 b = *reinterpret_cast<const float4*>(&Bs[k][tx * 4]);
            float aa[4] = {a.x, a.y, a.z, a.w}, bb[4] = {b.x, b.y, b.z, b.w};
#pragma unroll
            for (int j = 0; j < 4; j++)
#pragma unroll
                for (int i = 0; i < 4; i++) acc[j][i] += aa[j] * bb[i];
        }
        __syncthreads();
    }
#pragma unroll
    for (int j = 0; j < 4; j++) {
        int m = m0 + ty * 4 + j;
#pragma unroll
        for (int i = 0; i < 4; i++)
            Cf[(size_t)m * N + n0 + tx * 4 + i] = acc[j][i];
    }
}

// KW = rowscale(keys) @ Wqp, fp64 accumulate; writes fp64 KW and fp32 KWf.
__global__ __launch_bounds__(256) void gemm_ab_f64(
    const void* __restrict__ A, const void* __restrict__ B,
    const void* __restrict__ gdet, const double* __restrict__ inv_kd,
    double* __restrict__ Cd, float* __restrict__ Cf, int M, int N, int K)
{
    __shared__ float As[32][68];
    __shared__ float Bs[32][68];
    const int bf = detect_bf(gdet);
    const int t = threadIdx.x;
    const int m0 = blockIdx.y * 64, n0 = blockIdx.x * 64;
    const int r = t & 63, kc = (t >> 6) * 8;
    const int tx = t & 15, kr = t >> 4;
    const int ty = t >> 4;
    double acc[4][4];
#pragma unroll
    for (int j = 0; j < 4; j++)
#pragma unroll
        for (int i = 0; i < 4; i++) acc[j][i] = 0.0;

    for (int k0 = 0; k0 < K; k0 += 32) {
        float av[8], bv0[4], bv1[4];
        ld4(A, (size_t)(m0 + r) * K + k0 + kc,     bf, av);
        ld4(A, (size_t)(m0 + r) * K + k0 + kc + 4, bf, av + 4);
        ld4(B, (size_t)(k0 + kr) * N + n0 + tx * 4,      bf, bv0);
        ld4(B, (size_t)(k0 + kr + 16) * N + n0 + tx * 4, bf, bv1);
#pragma unroll
        for (int j = 0; j < 8; j++) As[kc + j][r] = av[j];
        *reinterpret_cast<float4*>(&Bs[kr][tx * 4])      = make_float4(bv0[0], bv0[1], bv0[2], bv0[3]);
        *reinterpret_cast<float4*>(&Bs[kr + 16][tx * 4]) = make_float4(bv1[0], bv1[1], bv1[2], bv1[3]);
        __syncthreads();
#pragma unroll
        for (int k = 0; k < 32; k++) {
            float4 a = *reinterpret_cast<const float4*>(&As[k][ty * 4]);
            float4 b = *reinterpret_cast<const float4*>(&Bs[k][tx * 4]);
            float aa[4] = {a.x, a.y, a.z, a.w}, bb[4] = {b.x, b.y, b.z, b.w};
#pragma unroll
            for (int j = 0; j < 4; j++)
#pragma unroll
                for (int i = 0; i < 4; i++) acc[j][i] += (double)aa[j] * (double)bb[i];
        }
        __syncthreads();
    }
#pragma unroll
    for (int j = 0; j < 4; j++) {
        int m = m0 + ty * 4 + j;
#pragma unroll
        for (int i = 0; i < 4; i++) {
            double v = acc[j][i] * inv_kd[m];
            Cd[(size_t)m * N + n0 + tx * 4 + i] = v;
            Cf[(size_t)m * N + n0 + tx * 4 + i] = (float)v;
        }
    }
}

// ---------------------------------------------------------------------------
// C = [rowscale(A)] @ B^T. BM=BN=64, BK=32, 256 threads, 4x4 micro.
// amode/bmode: 1 -> dtype follows gdet, 0 -> fp32. epi 0: fp32 C. epi 1: (+bias)->O.
// ---------------------------------------------------------------------------
__global__ __launch_bounds__(256) void gemm_abt(
    const void* __restrict__ A, const void* __restrict__ B,
    const float* __restrict__ As_scale,
    float* __restrict__ C, const void* __restrict__ bias, void* __restrict__ O,
    int M, int N, int K, int amode, int bmode, int epi,
    const void* __restrict__ gdet)
{
    __shared__ float As[32][68];
    __shared__ float Bs[32][68];
    const int flag = detect_bf(gdet);
    const int abf = amode ? flag : 0;
    const int bbf = bmode ? flag : 0;
    const int t = threadIdx.x;
    const int m0 = blockIdx.y * 64, n0 = blockIdx.x * 64;
    const int r = t & 63, kc = (t >> 6) * 8;
    const int tx = t & 15, ty = t >> 4;
    const float sc = As_scale ? As_scale[m0 + r] : 1.0f;
    float acc[4][4];
#pragma unroll
    for (int j = 0; j < 4; j++)
#pragma unroll
        for (int i = 0; i < 4; i++) acc[j][i] = 0.f;

    for (int k0 = 0; k0 < K; k0 += 32) {
        float av[8], bv[8];
        ld4(A, (size_t)(m0 + r) * K + k0 + kc,     abf, av);
        ld4(A, (size_t)(m0 + r) * K + k0 + kc + 4, abf, av + 4);
        ld4(B, (size_t)(n0 + r) * K + k0 + kc,     bbf, bv);
        ld4(B, (size_t)(n0 + r) * K + k0 + kc + 4, bbf, bv + 4);
#pragma unroll
        for (int j = 0; j < 8; j++) As[kc + j][r] = av[j] * sc;
#pragma unroll
        for (int j = 0; j < 8; j++) Bs[kc + j][r] = bv[j];
        __syncthreads();
#pragma unroll
        for (int k = 0; k < 32; k++) {
            float4 a = *reinterpret_cast<const float4*>(&As[k][ty * 4]);
            float4 b = *reinterpret_cast<const float4*>(&Bs[k][tx * 4]);
            float aa[4] = {a.x, a.y, a.z, a.w}, bb[4] = {b.x, b.y, b.z, b.w};
#pragma unroll
            for (int j = 0; j < 4; j++)
#pragma unroll
                for (int i = 0; i < 4; i++) acc[j][i] += aa[j] * bb[i];
        }
        __syncthreads();
    }
#pragma unroll
    for (int j = 0; j < 4; j++) {
        int m = m0 + ty * 4 + j;
        int n = n0 + tx * 4;
        size_t off = (size_t)m * N + n;
        if (epi == 0) {
            *reinterpret_cast<float4*>(&C[off]) =
                make_float4(acc[j][0], acc[j][1], acc[j][2], acc[j][3]);
        } else {
            float o4[4];
#pragma unroll
            for (int i = 0; i < 4; i++)
                o4[i] = acc[j][i] + (bias ? ldg1(bias, n + i, flag) : 0.f);
            if (flag) {
                ushort4 u = make_ushort4(f2bf(o4[0]), f2bf(o4[1]), f2bf(o4[2]), f2bf(o4[3]));
                *reinterpret_cast<ushort4*>((unsigned short*)O + off) = u;
            } else {
                *reinterpret_cast<float4*>((float*)O + off) =
                    make_float4(o4[0], o4[1], o4[2], o4[3]);
            }
        }
    }
}

// ---------------------------------------------------------------------------
// Merged Kp/Vp projection: blockIdx.y<16 -> Kp from keys/Wk, else Vp from vals/Wv.
// ---------------------------------------------------------------------------
__global__ __launch_bounds__(256) void gemm_kv(
    const void* __restrict__ keys, const void* __restrict__ Wk,
    const float* __restrict__ kscale, float* __restrict__ Kp,
    const void* __restrict__ vals, const void* __restrict__ Wv,
    const float* __restrict__ vscale, float* __restrict__ Vp,
    const void* __restrict__ gdet)
{
    __shared__ float As[32][68];
    __shared__ float Bs[32][68];
    const int bf = detect_bf(gdet);
    const int t = threadIdx.x;
    int by = blockIdx.y;
    const void* A; const void* B; const float* scale; float* C;
    if (by < 16) { A = keys; B = Wk; scale = kscale; C = Kp; }
    else         { A = vals; B = Wv; scale = vscale; C = Vp; by -= 16; }
    const int m0 = by * 64, n0 = blockIdx.x * 64;
    const int r = t & 63, kc = (t >> 6) * 8;
    const int tx = t & 15, ty = t >> 4;
    const float sc = scale[m0 + r];
    float acc[4][4];
#pragma unroll
    for (int j = 0; j < 4; j++)
#pragma unroll
        for (int i = 0; i < 4; i++) acc[j][i] = 0.f;

    for (int k0 = 0; k0 < 512; k0 += 32) {
        float av[8], bv[8];
        ld4(A, (size_t)(m0 + r) * 512 + k0 + kc,     bf, av);
        ld4(A, (size_t)(m0 + r) * 512 + k0 + kc + 4, bf, av + 4);
        ld4(B, (size_t)(n0 + r) * 512 + k0 + kc,     bf, bv);
        ld4(B, (size_t)(n0 + r) * 512 + k0 + kc + 4, bf, bv + 4);
#pragma unroll
        for (int j = 0; j < 8; j++) As[kc + j][r] = av[j] * sc;
#pragma unroll
        for (int j = 0; j < 8; j++) Bs[kc + j][r] = bv[j];
        __syncthreads();
#pragma unroll
        for (int k = 0; k < 32; k++) {
            float4 a = *reinterpret_cast<const float4*>(&As[k][ty * 4]);
            float4 b = *reinterpret_cast<const float4*>(&Bs[k][tx * 4]);
            float aa[4] = {a.x, a.y, a.z, a.w}, bb[4] = {b.x, b.y, b.z, b.w};
#pragma unroll
            for (int j = 0; j < 4; j++)
#pragma unroll
                for (int i = 0; i < 4; i++) acc[j][i] += aa[j] * bb[i];
        }
        __syncthreads();
    }
#pragma unroll
    for (int j = 0; j < 4; j++) {
        size_t off = (size_t)(m0 + ty * 4 + j) * 512 + n0 + tx * 4;
        *reinterpret_cast<float4*>(&C[off]) =
            make_float4(acc[j][0], acc[j][1], acc[j][2], acc[j][3]);
    }
}

// ---------------------------------------------------------------------------
// Top-32 select, one wave per row (4 rows / 256-thread block).
// Bisection over LDS-resident monotone keys; compaction; 64-lane shuffle
// bitonic; margin test; rare LANE-PARALLEL fp64 exact rescore (no serial
// shuffle chains) + one 64-lane bitonic on doubles.
// ---------------------------------------------------------------------------
__global__ __launch_bounds__(256) void topk_select(
    const float* __restrict__ Sc, const void* __restrict__ X,
    const void* __restrict__ gdet, const double* __restrict__ KW,
    int* __restrict__ idx)
{
    __shared__ unsigned int srow[4][1024];
    __shared__ unsigned int scv[4][64];
    __shared__ int          sci[4][64];
    const int bf = detect_bf(gdet);
    const int w = threadIdx.x >> 6, lane = threadIdx.x & 63;
    const int row = blockIdx.x * 4 + w;
    const float* S = Sc + (size_t)row * 1024;

#pragma unroll
    for (int q = 0; q < 4; q++) {
        float4 v = *reinterpret_cast<const float4*>(&S[lane * 4 + q * 256]);
        uint4 k = make_uint4(fkey(v.x), fkey(v.y), fkey(v.z), fkey(v.w));
        *reinterpret_cast<uint4*>(&srow[w][lane * 4 + q * 256]) = k;
    }
    scv[w][lane] = 0u;
    sci[w][lane] = 0x7FFFFFFF;
    __syncthreads();

    // bisection: invariant count(>=lo) >= 33, count(>=hi) < 33
    unsigned int lo = 0u, hi = 0xFFFFFFFFu;
    int cnt_lo = 1024;
    while (cnt_lo > 48 && hi - lo > 1u) {
        unsigned int mid = lo + ((hi - lo) >> 1);
        int c = 0;
#pragma unroll
        for (int q = 0; q < 4; q++) {
            uint4 k = *reinterpret_cast<const uint4*>(&srow[w][lane * 4 + q * 256]);
            c += (k.x >= mid) + (k.y >= mid) + (k.z >= mid) + (k.w >= mid);
        }
#pragma unroll
        for (int o = 1; o < 64; o <<= 1) c += __shfl_xor(c, o, 64);
        if (c >= 33) { lo = mid; cnt_lo = c; }
        else hi = mid;
    }
    const unsigned int T = lo;

    int cl = 0;
#pragma unroll
    for (int q = 0; q < 4; q++) {
        uint4 k = *reinterpret_cast<const uint4*>(&srow[w][lane * 4 + q * 256]);
        cl += (k.x >= T) + (k.y >= T) + (k.z >= T) + (k.w >= T);
    }
    int inc = cl;
#pragma unroll
    for (int o = 1; o < 64; o <<= 1) {
        int y = __shfl_up(inc, o, 64);
        if (lane >= o) inc += y;
    }
    int pos = inc - cl;
#pragma unroll
    for (int q = 0; q < 4; q++) {
        uint4 k = *reinterpret_cast<const uint4*>(&srow[w][lane * 4 + q * 256]);
        int base = lane * 4 + q * 256;
        if (k.x >= T && pos < 64) { scv[w][pos] = k.x; sci[w][pos] = base + 0; pos++; }
        if (k.y >= T && pos < 64) { scv[w][pos] = k.y; sci[w][pos] = base + 1; pos++; }
        if (k.z >= T && pos < 64) { scv[w][pos] = k.z; sci[w][pos] = base + 2; pos++; }
        if (k.w >= T && pos < 64) { scv[w][pos] = k.w; sci[w][pos] = base + 3; pos++; }
    }
    __syncthreads();
    unsigned int cv = scv[w][lane];
    int          ci = sci[w][lane];
#pragma unroll
    for (int k = 2; k <= 64; k <<= 1) {
#pragma unroll
        for (int jj = k >> 1; jj > 0; jj >>= 1) {
            unsigned int ov = __shfl_xor(cv, jj, 64);
            int          oi = __shfl_xor(ci, jj, 64);
            bool up = ((lane & k) == 0);
            bool takemax = (((lane & jj) == 0) == up);
            bool othergreater = (ov > cv) || (ov == cv && oi < ci);
            if (takemax == othergreater) { cv = ov; ci = oi; }
        }
    }
    float v31 = funkey(__shfl(cv, 31, 64));   // 32nd largest
    float v32 = funkey(__shfl(cv, 32, 64));   // 33rd largest (cnt>=33 -> real)
    if (v31 - v32 > 1e-4f) {
        if (lane < 32) idx[(size_t)row * 32 + lane] = ci;
        return;
    }
    // rare boundary row: lane-parallel exact fp64 rescore. Lane c owns the
    // c-th largest candidate; X[row,d] is lane-uniform (broadcast load).
    size_t xb = (size_t)row * 320;
    bool active = (lane < 48) && (ci != 0x7FFFFFFF);
    int cidx = active ? ci : 0x7FFFFFFF;
    const double* kr = KW + (size_t)(active ? ci : 0) * 320;
    double s = 0.0;
#pragma unroll 4
    for (int d = 0; d < 320; d++) {
        float xd = ldg1(X, xb + d, bf);
        s += (double)xd * kr[d];
    }
    if (!active) s = -1.0e300;
    // 64-lane bitonic sort descending by (s desc, cidx asc)
#pragma unroll
    for (int k = 2; k <= 64; k <<= 1) {
#pragma unroll
        for (int jj = k >> 1; jj > 0; jj >>= 1) {
            double os = __shfl_xor(s, jj, 64);
            int    oi = __shfl_xor(cidx, jj, 64);
            bool up = ((lane & k) == 0);
            bool takemax = (((lane & jj) == 0) == up);
            bool og = (os > s) || (os == s && oi < cidx);
            if (takemax == og) { s = os; cidx = oi; }
        }
    }
    if (lane < 32) idx[(size_t)row * 32 + lane] = cidx;
}

// ---------------------------------------------------------------------------
// Fused gather + 8-head attention per row. float4 QK, float2 PV.
// ---------------------------------------------------------------------------
__global__ __launch_bounds__(256) void attn_kernel(
    const float* __restrict__ qh, const float* __restrict__ Kp,
    const float* __restrict__ Vp, const int* __restrict__ idx,
    float* __restrict__ ctx)
{
    __shared__ float sq[512];
    __shared__ int   sidx[32];
    __shared__ float sl[8][32];
    __shared__ float sw[8][32];
    int row = blockIdx.x, t = threadIdx.x;
    if (t < 128)
        *reinterpret_cast<float4*>(&sq[t * 4]) =
            *reinterpret_cast<const float4*>(&qh[(size_t)row * 512 + t * 4]);
    if (t < 32) {
        int v = idx[(size_t)row * 32 + t];
        sidx[t] = (v < 0) ? 0 : (v > 1023 ? 1023 : v);
    }
    __syncthreads();

    int h = t >> 5, k = t & 31;
    const float* kp = Kp + (size_t)sidx[k] * 512 + h * 64;
    float acc = 0.f;
#pragma unroll
    for (int d = 0; d < 16; d++) {
        float4 a = *reinterpret_cast<const float4*>(&sq[h * 64 + d * 4]);
        float4 b = *reinterpret_cast<const float4*>(&kp[d * 4]);
        acc += a.x * b.x + a.y * b.y + a.z * b.z + a.w * b.w;
    }
    float logit = acc * 0.125f;
    sl[h][k] = logit;
    __syncthreads();
    float m = -1e30f;
#pragma unroll
    for (int i = 0; i < 32; i++) m = fmaxf(m, sl[h][i]);
    float ssum = 0.f;
#pragma unroll
    for (int i = 0; i < 32; i++) ssum += __expf(sl[h][i] - m);
    sw[h][k] = __expf(logit - m) / ssum;
    __syncthreads();

    int c = t * 2, hh = c >> 6;
    float ax = 0.f, ay = 0.f;
#pragma unroll
    for (int kk = 0; kk < 32; kk++) {
        float2 vv = *reinterpret_cast<const float2*>(&Vp[(size_t)sidx[kk] * 512 + c]);
        float wgt = sw[hh][kk];
        ax += wgt * vv.x; ay += wgt * vv.y;
    }
    *reinterpret_cast<float2*>(&ctx[(size_t)row * 512 + c]) = make_float2(ax, ay);
}

// ---------------------------------------------------------------------------
// Per-row LayerNorm stats (mu, 1/sigma), fp64 reduce, one wave per row.
// ---------------------------------------------------------------------------
__global__ __launch_bounds__(256) void ln_stats(
    const float* __restrict__ co, float2* __restrict__ stats)
{
    int w = threadIdx.x >> 6, lane = threadIdx.x & 63;
    int row = blockIdx.x * 4 + w;
    const float* p = co + (size_t)row * 512;
    float4 a = *reinterpret_cast<const float4*>(&p[lane * 8]);
    float4 b = *reinterpret_cast<const float4*>(&p[lane * 8 + 4]);
    double s  = (double)a.x + (double)a.y + (double)a.z + (double)a.w
              + (double)b.x + (double)b.y + (double)b.z + (double)b.w;
    double ss = (double)a.x * a.x + (double)a.y * a.y + (double)a.z * a.z
              + (double)a.w * a.w + (double)b.x * b.x + (double)b.y * b.y
              + (double)b.z * b.z + (double)b.w * b.w;
#pragma unroll
    for (int o = 1; o < 64; o <<= 1) {
        s  += __shfl_xor(s, o, 64);
        ss += __shfl_xor(ss, o, 64);
    }
    if (lane == 0) {
        double mu = s / 512.0, var = ss / 512.0 - mu * mu;
        stats[row] = make_float2((float)mu, (float)(1.0 / sqrt(var + 1e-5)));
    }
}

// ---------------------------------------------------------------------------
// Output GEMM with fused LayerNorm on A: out = LN(co)*g+b @ Wout^T + bout.
// M=4096, N=320, K=512.
// ---------------------------------------------------------------------------
__global__ __launch_bounds__(256) void gemm_out(
    const float* __restrict__ co, const float2* __restrict__ stats,
    const void* __restrict__ g, const void* __restrict__ bvec,
    const void* __restrict__ Wout, const void* __restrict__ bout,
    void* __restrict__ O, const void* __restrict__ gdet)
{
    __shared__ float As[32][68];
    __shared__ float Bs[32][68];
    const int bf = detect_bf(gdet);
    const int t = threadIdx.x;
    const int m0 = blockIdx.y * 64, n0 = blockIdx.x * 64;
    const int r = t & 63, kc = (t >> 6) * 8;
    const int tx = t & 15, ty = t >> 4;
    const float2 st = stats[m0 + r];
    float acc[4][4];
#pragma unroll
    for (int j = 0; j < 4; j++)
#pragma unroll
        for (int i = 0; i < 4; i++) acc[j][i] = 0.f;

    for (int k0 = 0; k0 < 512; k0 += 32) {
        float av[8], bw[8], gv[8], bv8[8];
        ld4(co,   (size_t)(m0 + r) * 512 + k0 + kc,     0, av);
        ld4(co,   (size_t)(m0 + r) * 512 + k0 + kc + 4, 0, av + 4);
        ld4(g,    (size_t)(k0 + kc),     bf, gv);
        ld4(g,    (size_t)(k0 + kc + 4), bf, gv + 4);
        ld4(bvec, (size_t)(k0 + kc),     bf, bv8);
        ld4(bvec, (size_t)(k0 + kc + 4), bf, bv8 + 4);
        ld4(Wout, (size_t)(n0 + r) * 512 + k0 + kc,     bf, bw);
        ld4(Wout, (size_t)(n0 + r) * 512 + k0 + kc + 4, bf, bw + 4);
#pragma unroll
        for (int j = 0; j < 8; j++)
            As[kc + j][r] = (av[j] - st.x) * st.y * gv[j] + bv8[j];
#pragma unroll
        for (int j = 0; j < 8; j++) Bs[kc + j][r] = bw[j];
        __syncthreads();
#pragma unroll
        for (int k = 0; k < 32; k++) {
            float4 a = *reinterpret_cast<const float4*>(&As[k][ty * 4]);
            float4 b = *reinterpret_cast<const float4*>(&Bs[k][tx * 4]);
            float aa[4] = {a.x, a.y, a.z, a.w}, bb[4] = {b.x, b.y, b.z, b.w};
#pragma unroll
            for (int j = 0; j < 4; j++)
#pragma unroll
                for (int i = 0; i < 4; i++) acc[j][i] += aa[j] * bb[i];
        }
        __syncthreads();
    }
#pragma unroll
    for (int j = 0; j < 4; j++) {
        int m = m0 + ty * 4 + j;
        int n = n0 + tx * 4;
        size_t off = (size_t)m * 320 + n;
        float o4[4];
#pragma unroll
        for (int i = 0; i < 4; i++) o4[i] = acc[j][i] + ldg1(bout, n + i, bf);
        if (bf) {
            ushort4 u = make_ushort4(f2bf(o4[0]), f2bf(o4[1]), f2bf(o4[2]), f2bf(o4[3]));
            *reinterpret_cast<ushort4*>((unsigned short*)O + off) = u;
        } else {
            *reinterpret_cast<float4*>((float*)O + off) =
                make_float4(o4[0], o4[1], o4[2], o4[3]);
        }
    }
}

extern "C" void kernel_launch(void* const* d_in, const int* in_sizes, int n_in,
                              void* d_out, int out_size, void* d_ws, size_t ws_size,
                              hipStream_t stream)
{
    const void* X    = d_in[0];
    const void* Wqp  = d_in[1];
    const void* keys = d_in[2];
    const void* vals = d_in[3];
    const void* Wq   = d_in[4];
    const void* Wk   = d_in[5];
    const void* Wv   = d_in[6];
    const void* Wo   = d_in[7];
    const void* ln_g = d_in[8];
    const void* ln_b = d_in[9];
    const void* Wout = d_in[10];
    const void* bout = d_in[11];

    // ---- workspace (float units; ~23.0 MiB) ----
    float* ws = (float*)d_ws;
    float*  Sc     = ws;                       // 4096x1024 fp32
    float*  Xreg   = ws;                       // 2,097,152: qh -> co
    float*  Yreg   = ws + 2097152;             // 2,097,152: ctx -> stats
    float*  Mf     = ws + 4194304;             // (Kp region; Mf dead before Kp)
    float*  Kp     = ws + 4194304;             // 524,288
    float*  KWf    = ws + 4718592;             // (Vp region; KWf dead before Vp)
    float*  Vp     = ws + 4718592;             // 524,288
    double* KW     = (double*)(ws + 5242880);  // 1024*320 dbl
    int*    idx    = (int*)(ws + 5898240);     // 131,072
    double* inv_kd = (double*)(ws + 6029312);
    float*  inv_kf = ws + 6031360;
    float*  inv_vf = ws + 6032384;
    float*  qh     = Xreg;
    float*  co     = Xreg;                     // qh dead after attn
    float*  ctx    = Yreg;
    float2* stats  = (float2*)Yreg;            // ctx dead after co-gemm

    norms_kernel<<<2048, 256, 0, stream>>>(keys, vals, ln_g, inv_kd, inv_kf, inv_vf);
    gemm_ab_f64<<<dim3(5, 16), 256, 0, stream>>>(
        keys, Wqp, ln_g, inv_kd, KW, KWf, 1024, 320, 512);
    gemm_ab<<<dim3(5, 8), 256, 0, stream>>>(Wq, Wqp, ln_g, Mf, 512, 320, 512);
    gemm_abt<<<dim3(16, 64), 256, 0, stream>>>(
        X, KWf, nullptr, Sc, nullptr, nullptr, 4096, 1024, 320, 1, 0, 0, ln_g);
    topk_select<<<1024, 256, 0, stream>>>(Sc, X, ln_g, KW, idx);
    gemm_abt<<<dim3(8, 64), 256, 0, stream>>>(
        X, Mf, nullptr, qh, nullptr, nullptr, 4096, 512, 320, 1, 0, 0, ln_g);
    gemm_kv<<<dim3(8, 32), 256, 0, stream>>>(
        keys, Wk, inv_kf, Kp, vals, Wv, inv_vf, Vp, ln_g);
    attn_kernel<<<4096, 256, 0, stream>>>(qh, Kp, Vp, idx, ctx);
    gemm_abt<<<dim3(8, 64), 256, 0, stream>>>(
        ctx, Wo, nullptr, co, nullptr, nullptr, 4096, 512, 512, 0, 1, 0, ln_g);
    ln_stats<<<1024, 256, 0, stream>>>(co, stats);
    gemm_out<<<dim3(5, 64), 256, 0, stream>>>(
        co, stats, ln_g, ln_b, Wout, bout, d_out, ln_g);
}

// Round 9
// 411.465 us; speedup vs baseline: 3.1215x; 1.0430x over previous
//
#include <hip/hip_runtime.h>

// GatedLTMMemory: 4096 rows, QD=320, D=512, S=1024, H=8, K=32, DH=64
// Dtype (fp32 vs bf16) derived inline from ln_g[0] (== 1.0). (Resolved: fp32.)

__device__ __forceinline__ float bf2f(unsigned short u) {
    return __uint_as_float(((unsigned int)u) << 16);
}
__device__ __forceinline__ unsigned short f2bf(float f) {
    unsigned int u = __float_as_uint(f);
    u += 0x7FFFu + ((u >> 16) & 1u);
    return (unsigned short)(u >> 16);
}
__device__ __forceinline__ int detect_bf(const void* g) {
    return ((*(const unsigned int*)g) & 0xFFFFu) != 0u;
}
__device__ __forceinline__ float ldg1(const void* p, size_t i, int bf) {
    return bf ? bf2f(((const unsigned short*)p)[i]) : ((const float*)p)[i];
}
__device__ __forceinline__ void ld4(const void* p, size_t i, int bf, float* o) {
    if (bf) {
        ushort4 v = *reinterpret_cast<const ushort4*>((const unsigned short*)p + i);
        o[0] = bf2f(v.x); o[1] = bf2f(v.y); o[2] = bf2f(v.z); o[3] = bf2f(v.w);
    } else {
        float4 v = *reinterpret_cast<const float4*>((const float*)p + i);
        o[0] = v.x; o[1] = v.y; o[2] = v.z; o[3] = v.w;
    }
}
__device__ __forceinline__ unsigned int fkey(float x) {
    unsigned int u = __float_as_uint(x);
    return (u & 0x80000000u) ? ~u : (u | 0x80000000u);
}
__device__ __forceinline__ float funkey(unsigned int k) {
    unsigned int u = (k & 0x80000000u) ? (k & 0x7FFFFFFFu) : ~k;
    return __uint_as_float(u);
}

__global__ __launch_bounds__(256) void norms_kernel(
    const void* __restrict__ keys, const void* __restrict__ vals,
    const void* __restrict__ gdet,
    double* __restrict__ inv_kd, float* __restrict__ inv_kf, float* __restrict__ inv_vf)
{
    __shared__ double red[256];
    int bf = detect_bf(gdet);
    int r = blockIdx.x, t = threadIdx.x;
    const void* src = (r < 1024) ? keys : vals;
    size_t base = (size_t)((r < 1024) ? r : r - 1024) * 512;
    float x0 = ldg1(src, base + t, bf), x1 = ldg1(src, base + t + 256, bf);
    red[t] = (double)x0 * x0 + (double)x1 * x1;
    __syncthreads();
    for (int s = 128; s > 0; s >>= 1) {
        if (t < s) red[t] += red[t + s];
        __syncthreads();
    }
    if (t == 0) {
        double rs = 1.0 / sqrt(red[0] + 1e-12);
        if (r < 1024) { inv_kd[r] = rs; inv_kf[r] = (float)rs; }
        else          { inv_vf[r - 1024] = (float)rs; }
    }
}

// ---------------------------------------------------------------------------
// C = A @ B (B row-major [K,N]) fp32. BM=BN=64, BK=32, 256 threads, 4x4 micro.
// ---------------------------------------------------------------------------
__global__ __launch_bounds__(256) void gemm_ab(
    const void* __restrict__ A, const void* __restrict__ B,
    const void* __restrict__ gdet, float* __restrict__ Cf, int M, int N, int K)
{
    __shared__ float As[32][68];
    __shared__ float Bs[32][68];
    const int bf = detect_bf(gdet);
    const int t = threadIdx.x;
    const int m0 = blockIdx.y * 64, n0 = blockIdx.x * 64;
    const int r = t & 63, kc = (t >> 6) * 8;
    const int tx = t & 15, kr = t >> 4;
    const int ty = t >> 4;
    float acc[4][4];
#pragma unroll
    for (int j = 0; j < 4; j++)
#pragma unroll
        for (int i = 0; i < 4; i++) acc[j][i] = 0.f;

    for (int k0 = 0; k0 < K; k0 += 32) {
        float av[8], bv0[4], bv1[4];
        ld4(A, (size_t)(m0 + r) * K + k0 + kc,     bf, av);
        ld4(A, (size_t)(m0 + r) * K + k0 + kc + 4, bf, av + 4);
        ld4(B, (size_t)(k0 + kr) * N + n0 + tx * 4,      bf, bv0);
        ld4(B, (size_t)(k0 + kr + 16) * N + n0 + tx * 4, bf, bv1);
#pragma unroll
        for (int j = 0; j < 8; j++) As[kc + j][r] = av[j];
        *reinterpret_cast<float4*>(&Bs[kr][tx * 4])      = make_float4(bv0[0], bv0[1], bv0[2], bv0[3]);
        *reinterpret_cast<float4*>(&Bs[kr + 16][tx * 4]) = make_float4(bv1[0], bv1[1], bv1[2], bv1[3]);
        __syncthreads();
#pragma unroll
        for (int k = 0; k < 32; k++) {
            float4 a = *reinterpret_cast<const float4*>(&As[k][ty * 4]);
            float4 b = *reinterpret_cast<const float4*>(&Bs[k][tx * 4]);
            float aa[4] = {a.x, a.y, a.z, a.w}, bb[4] = {b.x, b.y, b.z, b.w};
#pragma unroll
            for (int j = 0; j < 4; j++)
#pragma unroll
                for (int i = 0; i < 4; i++) acc[j][i] += aa[j] * bb[i];
        }
        __syncthreads();
    }
#pragma unroll
    for (int j = 0; j < 4; j++) {
        int m = m0 + ty * 4 + j;
#pragma unroll
        for (int i = 0; i < 4; i++)
            Cf[(size_t)m * N + n0 + tx * 4 + i] = acc[j][i];
    }
}

// KW = rowscale(keys) @ Wqp, fp64 accumulate; writes fp64 KW and fp32 KWf.
__global__ __launch_bounds__(256) void gemm_ab_f64(
    const void* __restrict__ A, const void* __restrict__ B,
    const void* __restrict__ gdet, const double* __restrict__ inv_kd,
    double* __restrict__ Cd, float* __restrict__ Cf, int M, int N, int K)
{
    __shared__ float As[32][68];
    __shared__ float Bs[32][68];
    const int bf = detect_bf(gdet);
    const int t = threadIdx.x;
    const int m0 = blockIdx.y * 64, n0 = blockIdx.x * 64;
    const int r = t & 63, kc = (t >> 6) * 8;
    const int tx = t & 15, kr = t >> 4;
    const int ty = t >> 4;
    double acc[4][4];
#pragma unroll
    for (int j = 0; j < 4; j++)
#pragma unroll
        for (int i = 0; i < 4; i++) acc[j][i] = 0.0;

    for (int k0 = 0; k0 < K; k0 += 32) {
        float av[8], bv0[4], bv1[4];
        ld4(A, (size_t)(m0 + r) * K + k0 + kc,     bf, av);
        ld4(A, (size_t)(m0 + r) * K + k0 + kc + 4, bf, av + 4);
        ld4(B, (size_t)(k0 + kr) * N + n0 + tx * 4,      bf, bv0);
        ld4(B, (size_t)(k0 + kr + 16) * N + n0 + tx * 4, bf, bv1);
#pragma unroll
        for (int j = 0; j < 8; j++) As[kc + j][r] = av[j];
        *reinterpret_cast<float4*>(&Bs[kr][tx * 4])      = make_float4(bv0[0], bv0[1], bv0[2], bv0[3]);
        *reinterpret_cast<float4*>(&Bs[kr + 16][tx * 4]) = make_float4(bv1[0], bv1[1], bv1[2], bv1[3]);
        __syncthreads();
#pragma unroll
        for (int k = 0; k < 32; k++) {
            float4 a = *reinterpret_cast<const float4*>(&As[k][ty * 4]);
            float4 b = *reinterpret_cast<const float4*>(&Bs[k][tx * 4]);
            float aa[4] = {a.x, a.y, a.z, a.w}, bb[4] = {b.x, b.y, b.z, b.w};
#pragma unroll
            for (int j = 0; j < 4; j++)
#pragma unroll
                for (int i = 0; i < 4; i++) acc[j][i] += (double)aa[j] * (double)bb[i];
        }
        __syncthreads();
    }
#pragma unroll
    for (int j = 0; j < 4; j++) {
        int m = m0 + ty * 4 + j;
#pragma unroll
        for (int i = 0; i < 4; i++) {
            double v = acc[j][i] * inv_kd[m];
            Cd[(size_t)m * N + n0 + tx * 4 + i] = v;
            Cf[(size_t)m * N + n0 + tx * 4 + i] = (float)v;
        }
    }
}

// ---------------------------------------------------------------------------
// C = [rowscale(A)] @ B^T. BM=BN=64, BK=32, 256 threads, 4x4 micro.
// ---------------------------------------------------------------------------
__global__ __launch_bounds__(256) void gemm_abt(
    const void* __restrict__ A, const void* __restrict__ B,
    const float* __restrict__ As_scale,
    float* __restrict__ C, const void* __restrict__ bias, void* __restrict__ O,
    int M, int N, int K, int amode, int bmode, int epi,
    const void* __restrict__ gdet)
{
    __shared__ float As[32][68];
    __shared__ float Bs[32][68];
    const int flag = detect_bf(gdet);
    const int abf = amode ? flag : 0;
    const int bbf = bmode ? flag : 0;
    const int t = threadIdx.x;
    const int m0 = blockIdx.y * 64, n0 = blockIdx.x * 64;
    const int r = t & 63, kc = (t >> 6) * 8;
    const int tx = t & 15, ty = t >> 4;
    const float sc = As_scale ? As_scale[m0 + r] : 1.0f;
    float acc[4][4];
#pragma unroll
    for (int j = 0; j < 4; j++)
#pragma unroll
        for (int i = 0; i < 4; i++) acc[j][i] = 0.f;

    for (int k0 = 0; k0 < K; k0 += 32) {
        float av[8], bv[8];
        ld4(A, (size_t)(m0 + r) * K + k0 + kc,     abf, av);
        ld4(A, (size_t)(m0 + r) * K + k0 + kc + 4, abf, av + 4);
        ld4(B, (size_t)(n0 + r) * K + k0 + kc,     bbf, bv);
        ld4(B, (size_t)(n0 + r) * K + k0 + kc + 4, bbf, bv + 4);
#pragma unroll
        for (int j = 0; j < 8; j++) As[kc + j][r] = av[j] * sc;
#pragma unroll
        for (int j = 0; j < 8; j++) Bs[kc + j][r] = bv[j];
        __syncthreads();
#pragma unroll
        for (int k = 0; k < 32; k++) {
            float4 a = *reinterpret_cast<const float4*>(&As[k][ty * 4]);
            float4 b = *reinterpret_cast<const float4*>(&Bs[k][tx * 4]);
            float aa[4] = {a.x, a.y, a.z, a.w}, bb[4] = {b.x, b.y, b.z, b.w};
#pragma unroll
            for (int j = 0; j < 4; j++)
#pragma unroll
                for (int i = 0; i < 4; i++) acc[j][i] += aa[j] * bb[i];
        }
        __syncthreads();
    }
#pragma unroll
    for (int j = 0; j < 4; j++) {
        int m = m0 + ty * 4 + j;
        int n = n0 + tx * 4;
        size_t off = (size_t)m * N + n;
        if (epi == 0) {
            *reinterpret_cast<float4*>(&C[off]) =
                make_float4(acc[j][0], acc[j][1], acc[j][2], acc[j][3]);
        } else {
            float o4[4];
#pragma unroll
            for (int i = 0; i < 4; i++)
                o4[i] = acc[j][i] + (bias ? ldg1(bias, n + i, flag) : 0.f);
            if (flag) {
                ushort4 u = make_ushort4(f2bf(o4[0]), f2bf(o4[1]), f2bf(o4[2]), f2bf(o4[3]));
                *reinterpret_cast<ushort4*>((unsigned short*)O + off) = u;
            } else {
                *reinterpret_cast<float4*>((float*)O + off) =
                    make_float4(o4[0], o4[1], o4[2], o4[3]);
            }
        }
    }
}

// ---------------------------------------------------------------------------
// Sc = A @ B^T, BM=BN=128, BK=16, 256 threads, 8x8 micro (cols split tx*4 and
// tx*4+64 to keep LDS reads 2-way conflict-free). A dtype per gdet, B fp32.
// ---------------------------------------------------------------------------
__global__ __launch_bounds__(256) void gemm_sc128(
    const void* __restrict__ A, const float* __restrict__ B,
    const void* __restrict__ gdet, float* __restrict__ C, int M, int N, int K)
{
    __shared__ float As[16][132];
    __shared__ float Bs[16][132];
    const int bf = detect_bf(gdet);
    const int t = threadIdx.x;
    const int m0 = blockIdx.y * 128, n0 = blockIdx.x * 128;
    const int sr = t >> 1, sk = (t & 1) * 8;
    const int tx = t & 15, ty = t >> 4;
    float acc[8][8];
#pragma unroll
    for (int j = 0; j < 8; j++)
#pragma unroll
        for (int i = 0; i < 8; i++) acc[j][i] = 0.f;

    for (int k0 = 0; k0 < K; k0 += 16) {
        float av[8], bv[8];
        ld4(A, (size_t)(m0 + sr) * K + k0 + sk,     bf, av);
        ld4(A, (size_t)(m0 + sr) * K + k0 + sk + 4, bf, av + 4);
        ld4(B, (size_t)(n0 + sr) * K + k0 + sk,     0, bv);
        ld4(B, (size_t)(n0 + sr) * K + k0 + sk + 4, 0, bv + 4);
#pragma unroll
        for (int j = 0; j < 8; j++) As[sk + j][sr] = av[j];
#pragma unroll
        for (int j = 0; j < 8; j++) Bs[sk + j][sr] = bv[j];
        __syncthreads();
#pragma unroll
        for (int k = 0; k < 16; k++) {
            float4 a0 = *reinterpret_cast<const float4*>(&As[k][ty * 8]);
            float4 a1 = *reinterpret_cast<const float4*>(&As[k][ty * 8 + 4]);
            float4 b0 = *reinterpret_cast<const float4*>(&Bs[k][tx * 4]);
            float4 b1 = *reinterpret_cast<const float4*>(&Bs[k][tx * 4 + 64]);
            float aa[8] = {a0.x, a0.y, a0.z, a0.w, a1.x, a1.y, a1.z, a1.w};
            float bb[8] = {b0.x, b0.y, b0.z, b0.w, b1.x, b1.y, b1.z, b1.w};
#pragma unroll
            for (int j = 0; j < 8; j++)
#pragma unroll
                for (int i = 0; i < 8; i++) acc[j][i] += aa[j] * bb[i];
        }
        __syncthreads();
    }
#pragma unroll
    for (int j = 0; j < 8; j++) {
        int m = m0 + ty * 8 + j;
        *reinterpret_cast<float4*>(&C[(size_t)m * N + n0 + tx * 4]) =
            make_float4(acc[j][0], acc[j][1], acc[j][2], acc[j][3]);
        *reinterpret_cast<float4*>(&C[(size_t)m * N + n0 + 64 + tx * 4]) =
            make_float4(acc[j][4], acc[j][5], acc[j][6], acc[j][7]);
    }
}

// ---------------------------------------------------------------------------
// Merged Kp/Vp projection: blockIdx.y<16 -> Kp from keys/Wk, else Vp from vals/Wv.
// ---------------------------------------------------------------------------
__global__ __launch_bounds__(256) void gemm_kv(
    const void* __restrict__ keys, const void* __restrict__ Wk,
    const float* __restrict__ kscale, float* __restrict__ Kp,
    const void* __restrict__ vals, const void* __restrict__ Wv,
    const float* __restrict__ vscale, float* __restrict__ Vp,
    const void* __restrict__ gdet)
{
    __shared__ float As[32][68];
    __shared__ float Bs[32][68];
    const int bf = detect_bf(gdet);
    const int t = threadIdx.x;
    int by = blockIdx.y;
    const void* A; const void* B; const float* scale; float* C;
    if (by < 16) { A = keys; B = Wk; scale = kscale; C = Kp; }
    else         { A = vals; B = Wv; scale = vscale; C = Vp; by -= 16; }
    const int m0 = by * 64, n0 = blockIdx.x * 64;
    const int r = t & 63, kc = (t >> 6) * 8;
    const int tx = t & 15, ty = t >> 4;
    const float sc = scale[m0 + r];
    float acc[4][4];
#pragma unroll
    for (int j = 0; j < 4; j++)
#pragma unroll
        for (int i = 0; i < 4; i++) acc[j][i] = 0.f;

    for (int k0 = 0; k0 < 512; k0 += 32) {
        float av[8], bv[8];
        ld4(A, (size_t)(m0 + r) * 512 + k0 + kc,     bf, av);
        ld4(A, (size_t)(m0 + r) * 512 + k0 + kc + 4, bf, av + 4);
        ld4(B, (size_t)(n0 + r) * 512 + k0 + kc,     bf, bv);
        ld4(B, (size_t)(n0 + r) * 512 + k0 + kc + 4, bf, bv + 4);
#pragma unroll
        for (int j = 0; j < 8; j++) As[kc + j][r] = av[j] * sc;
#pragma unroll
        for (int j = 0; j < 8; j++) Bs[kc + j][r] = bv[j];
        __syncthreads();
#pragma unroll
        for (int k = 0; k < 32; k++) {
            float4 a = *reinterpret_cast<const float4*>(&As[k][ty * 4]);
            float4 b = *reinterpret_cast<const float4*>(&Bs[k][tx * 4]);
            float aa[4] = {a.x, a.y, a.z, a.w}, bb[4] = {b.x, b.y, b.z, b.w};
#pragma unroll
            for (int j = 0; j < 4; j++)
#pragma unroll
                for (int i = 0; i < 4; i++) acc[j][i] += aa[j] * bb[i];
        }
        __syncthreads();
    }
#pragma unroll
    for (int j = 0; j < 4; j++) {
        size_t off = (size_t)(m0 + ty * 4 + j) * 512 + n0 + tx * 4;
        *reinterpret_cast<float4*>(&C[off]) =
            make_float4(acc[j][0], acc[j][1], acc[j][2], acc[j][3]);
    }
}

// ---------------------------------------------------------------------------
// Top-32 select, one wave per row (4 rows / 256-thread block).
// ---------------------------------------------------------------------------
__global__ __launch_bounds__(256) void topk_select(
    const float* __restrict__ Sc, const void* __restrict__ X,
    const void* __restrict__ gdet, const double* __restrict__ KW,
    int* __restrict__ idx)
{
    __shared__ unsigned int srow[4][1024];
    __shared__ unsigned int scv[4][64];
    __shared__ int          sci[4][64];
    const int bf = detect_bf(gdet);
    const int w = threadIdx.x >> 6, lane = threadIdx.x & 63;
    const int row = blockIdx.x * 4 + w;
    const float* S = Sc + (size_t)row * 1024;

#pragma unroll
    for (int q = 0; q < 4; q++) {
        float4 v = *reinterpret_cast<const float4*>(&S[lane * 4 + q * 256]);
        uint4 k = make_uint4(fkey(v.x), fkey(v.y), fkey(v.z), fkey(v.w));
        *reinterpret_cast<uint4*>(&srow[w][lane * 4 + q * 256]) = k;
    }
    scv[w][lane] = 0u;
    sci[w][lane] = 0x7FFFFFFF;
    __syncthreads();

    unsigned int lo = 0u, hi = 0xFFFFFFFFu;
    int cnt_lo = 1024;
    while (cnt_lo > 48 && hi - lo > 1u) {
        unsigned int mid = lo + ((hi - lo) >> 1);
        int c = 0;
#pragma unroll
        for (int q = 0; q < 4; q++) {
            uint4 k = *reinterpret_cast<const uint4*>(&srow[w][lane * 4 + q * 256]);
            c += (k.x >= mid) + (k.y >= mid) + (k.z >= mid) + (k.w >= mid);
        }
#pragma unroll
        for (int o = 1; o < 64; o <<= 1) c += __shfl_xor(c, o, 64);
        if (c >= 33) { lo = mid; cnt_lo = c; }
        else hi = mid;
    }
    const unsigned int T = lo;

    int cl = 0;
#pragma unroll
    for (int q = 0; q < 4; q++) {
        uint4 k = *reinterpret_cast<const uint4*>(&srow[w][lane * 4 + q * 256]);
        cl += (k.x >= T) + (k.y >= T) + (k.z >= T) + (k.w >= T);
    }
    int inc = cl;
#pragma unroll
    for (int o = 1; o < 64; o <<= 1) {
        int y = __shfl_up(inc, o, 64);
        if (lane >= o) inc += y;
    }
    int pos = inc - cl;
#pragma unroll
    for (int q = 0; q < 4; q++) {
        uint4 k = *reinterpret_cast<const uint4*>(&srow[w][lane * 4 + q * 256]);
        int base = lane * 4 + q * 256;
        if (k.x >= T && pos < 64) { scv[w][pos] = k.x; sci[w][pos] = base + 0; pos++; }
        if (k.y >= T && pos < 64) { scv[w][pos] = k.y; sci[w][pos] = base + 1; pos++; }
        if (k.z >= T && pos < 64) { scv[w][pos] = k.z; sci[w][pos] = base + 2; pos++; }
        if (k.w >= T && pos < 64) { scv[w][pos] = k.w; sci[w][pos] = base + 3; pos++; }
    }
    __syncthreads();
    unsigned int cv = scv[w][lane];
    int          ci = sci[w][lane];
#pragma unroll
    for (int k = 2; k <= 64; k <<= 1) {
#pragma unroll
        for (int jj = k >> 1; jj > 0; jj >>= 1) {
            unsigned int ov = __shfl_xor(cv, jj, 64);
            int          oi = __shfl_xor(ci, jj, 64);
            bool up = ((lane & k) == 0);
            bool takemax = (((lane & jj) == 0) == up);
            bool othergreater = (ov > cv) || (ov == cv && oi < ci);
            if (takemax == othergreater) { cv = ov; ci = oi; }
        }
    }
    float v31 = funkey(__shfl(cv, 31, 64));
    float v32 = funkey(__shfl(cv, 32, 64));
    if (v31 - v32 > 1e-4f) {
        if (lane < 32) idx[(size_t)row * 32 + lane] = ci;
        return;
    }
    // lane-parallel exact fp64 rescore of the sorted candidates
    size_t xb = (size_t)row * 320;
    bool active = (lane < 48) && (ci != 0x7FFFFFFF);
    int cidx = active ? ci : 0x7FFFFFFF;
    const double* kr = KW + (size_t)(active ? ci : 0) * 320;
    double s = 0.0;
#pragma unroll 4
    for (int d = 0; d < 320; d++) {
        float xd = ldg1(X, xb + d, bf);
        s += (double)xd * kr[d];
    }
    if (!active) s = -1.0e300;
#pragma unroll
    for (int k = 2; k <= 64; k <<= 1) {
#pragma unroll
        for (int jj = k >> 1; jj > 0; jj >>= 1) {
            double os = __shfl_xor(s, jj, 64);
            int    oi = __shfl_xor(cidx, jj, 64);
            bool up = ((lane & k) == 0);
            bool takemax = (((lane & jj) == 0) == up);
            bool og = (os > s) || (os == s && oi < cidx);
            if (takemax == og) { s = os; cidx = oi; }
        }
    }
    if (lane < 32) idx[(size_t)row * 32 + lane] = cidx;
}

// ---------------------------------------------------------------------------
// Fused gather + 8-head attention per row. QK: one wave per slot-row,
// coalesced full-line reads + 8-lane-group shuffle reduce. PV: float2 cols.
// ---------------------------------------------------------------------------
__global__ __launch_bounds__(256) void attn_kernel(
    const float* __restrict__ qh, const float* __restrict__ Kp,
    const float* __restrict__ Vp, const int* __restrict__ idx,
    float* __restrict__ ctx)
{
    __shared__ float sq[512];
    __shared__ int   sidx[32];
    __shared__ float sl[8][32];
    __shared__ float sw[8][32];
    int row = blockIdx.x, t = threadIdx.x;
    int w = t >> 6, l = t & 63;
    if (t < 128)
        *reinterpret_cast<float4*>(&sq[t * 4]) =
            *reinterpret_cast<const float4*>(&qh[(size_t)row * 512 + t * 4]);
    if (t < 32) {
        int v = idx[(size_t)row * 32 + t];
        sidx[t] = (v < 0) ? 0 : (v > 1023 ? 1023 : v);
    }
    __syncthreads();

    // per-lane q fragment (8 floats), reused across all slots of this wave
    float4 q0 = *reinterpret_cast<const float4*>(&sq[l * 8]);
    float4 q1 = *reinterpret_cast<const float4*>(&sq[l * 8 + 4]);
    int h = l >> 3;
#pragma unroll
    for (int i = 0; i < 8; i++) {
        int s = w * 8 + i;
        const float* kp = Kp + (size_t)sidx[s] * 512 + l * 8;
        float4 k0 = *reinterpret_cast<const float4*>(kp);
        float4 k1 = *reinterpret_cast<const float4*>(kp + 4);
        float p = q0.x * k0.x + q0.y * k0.y + q0.z * k0.z + q0.w * k0.w
                + q1.x * k1.x + q1.y * k1.y + q1.z * k1.z + q1.w * k1.w;
        p += __shfl_xor(p, 1, 64);
        p += __shfl_xor(p, 2, 64);
        p += __shfl_xor(p, 4, 64);
        if ((l & 7) == 0) sl[h][s] = p * 0.125f;
    }
    __syncthreads();

    int hh = t >> 5, kk = t & 31;
    float logit = sl[hh][kk];
    float m = -1e30f;
#pragma unroll
    for (int i = 0; i < 32; i++) m = fmaxf(m, sl[hh][i]);
    float ssum = 0.f;
#pragma unroll
    for (int i = 0; i < 32; i++) ssum += __expf(sl[hh][i] - m);
    sw[hh][kk] = __expf(logit - m) / ssum;
    __syncthreads();

    int c = t * 2, hc = c >> 6;
    float ax = 0.f, ay = 0.f;
#pragma unroll
    for (int k2 = 0; k2 < 32; k2++) {
        float2 vv = *reinterpret_cast<const float2*>(&Vp[(size_t)sidx[k2] * 512 + c]);
        float wgt = sw[hc][k2];
        ax += wgt * vv.x; ay += wgt * vv.y;
    }
    *reinterpret_cast<float2*>(&ctx[(size_t)row * 512 + c]) = make_float2(ax, ay);
}

// ---------------------------------------------------------------------------
// Per-row LayerNorm stats (mu, 1/sigma), fp64 reduce, one wave per row.
// ---------------------------------------------------------------------------
__global__ __launch_bounds__(256) void ln_stats(
    const float* __restrict__ co, float2* __restrict__ stats)
{
    int w = threadIdx.x >> 6, lane = threadIdx.x & 63;
    int row = blockIdx.x * 4 + w;
    const float* p = co + (size_t)row * 512;
    float4 a = *reinterpret_cast<const float4*>(&p[lane * 8]);
    float4 b = *reinterpret_cast<const float4*>(&p[lane * 8 + 4]);
    double s  = (double)a.x + (double)a.y + (double)a.z + (double)a.w
              + (double)b.x + (double)b.y + (double)b.z + (double)b.w;
    double ss = (double)a.x * a.x + (double)a.y * a.y + (double)a.z * a.z
              + (double)a.w * a.w + (double)b.x * b.x + (double)b.y * b.y
              + (double)b.z * b.z + (double)b.w * b.w;
#pragma unroll
    for (int o = 1; o < 64; o <<= 1) {
        s  += __shfl_xor(s, o, 64);
        ss += __shfl_xor(ss, o, 64);
    }
    if (lane == 0) {
        double mu = s / 512.0, var = ss / 512.0 - mu * mu;
        stats[row] = make_float2((float)mu, (float)(1.0 / sqrt(var + 1e-5)));
    }
}

// ---------------------------------------------------------------------------
// Output GEMM with fused LayerNorm on A: out = (LN(co)*g+b) @ Wout^T + bout.
// ---------------------------------------------------------------------------
__global__ __launch_bounds__(256) void gemm_out(
    const float* __restrict__ co, const float2* __restrict__ stats,
    const void* __restrict__ g, const void* __restrict__ bvec,
    const void* __restrict__ Wout, const void* __restrict__ bout,
    void* __restrict__ O, const void* __restrict__ gdet)
{
    __shared__ float As[32][68];
    __shared__ float Bs[32][68];
    const int bf = detect_bf(gdet);
    const int t = threadIdx.x;
    const int m0 = blockIdx.y * 64, n0 = blockIdx.x * 64;
    const int r = t & 63, kc = (t >> 6) * 8;
    const int tx = t & 15, ty = t >> 4;
    const float2 st = stats[m0 + r];
    float acc[4][4];
#pragma unroll
    for (int j = 0; j < 4; j++)
#pragma unroll
        for (int i = 0; i < 4; i++) acc[j][i] = 0.f;

    for (int k0 = 0; k0 < 512; k0 += 32) {
        float av[8], bw[8], gv[8], bv8[8];
        ld4(co,   (size_t)(m0 + r) * 512 + k0 + kc,     0, av);
        ld4(co,   (size_t)(m0 + r) * 512 + k0 + kc + 4, 0, av + 4);
        ld4(g,    (size_t)(k0 + kc),     bf, gv);
        ld4(g,    (size_t)(k0 + kc + 4), bf, gv + 4);
        ld4(bvec, (size_t)(k0 + kc),     bf, bv8);
        ld4(bvec, (size_t)(k0 + kc + 4), bf, bv8 + 4);
        ld4(Wout, (size_t)(n0 + r) * 512 + k0 + kc,     bf, bw);
        ld4(Wout, (size_t)(n0 + r) * 512 + k0 + kc + 4, bf, bw + 4);
#pragma unroll
        for (int j = 0; j < 8; j++)
            As[kc + j][r] = (av[j] - st.x) * st.y * gv[j] + bv8[j];
#pragma unroll
        for (int j = 0; j < 8; j++) Bs[kc + j][r] = bw[j];
        __syncthreads();
#pragma unroll
        for (int k = 0; k < 32; k++) {
            float4 a = *reinterpret_cast<const float4*>(&As[k][ty * 4]);
            float4 b = *reinterpret_cast<const float4*>(&Bs[k][tx * 4]);
            float aa[4] = {a.x, a.y, a.z, a.w}, bb[4] = {b.x, b.y, b.z, b.w};
#pragma unroll
            for (int j = 0; j < 4; j++)
#pragma unroll
                for (int i = 0; i < 4; i++) acc[j][i] += aa[j] * bb[i];
        }
        __syncthreads();
    }
#pragma unroll
    for (int j = 0; j < 4; j++) {
        int m = m0 + ty * 4 + j;
        int n = n0 + tx * 4;
        size_t off = (size_t)m * 320 + n;
        float o4[4];
#pragma unroll
        for (int i = 0; i < 4; i++) o4[i] = acc[j][i] + ldg1(bout, n + i, bf);
        if (bf) {
            ushort4 u = make_ushort4(f2bf(o4[0]), f2bf(o4[1]), f2bf(o4[2]), f2bf(o4[3]));
            *reinterpret_cast<ushort4*>((unsigned short*)O + off) = u;
        } else {
            *reinterpret_cast<float4*>((float*)O + off) =
                make_float4(o4[0], o4[1], o4[2], o4[3]);
        }
    }
}

extern "C" void kernel_launch(void* const* d_in, const int* in_sizes, int n_in,
                              void* d_out, int out_size, void* d_ws, size_t ws_size,
                              hipStream_t stream)
{
    const void* X    = d_in[0];
    const void* Wqp  = d_in[1];
    const void* keys = d_in[2];
    const void* vals = d_in[3];
    const void* Wq   = d_in[4];
    const void* Wk   = d_in[5];
    const void* Wv   = d_in[6];
    const void* Wo   = d_in[7];
    const void* ln_g = d_in[8];
    const void* ln_b = d_in[9];
    const void* Wout = d_in[10];
    const void* bout = d_in[11];

    // ---- workspace (float units; ~23.0 MiB) ----
    float* ws = (float*)d_ws;
    float*  Sc     = ws;                       // 4096x1024 fp32
    float*  Xreg   = ws;                       // 2,097,152: qh -> co
    float*  Yreg   = ws + 2097152;             // 2,097,152: ctx -> stats
    float*  Mf     = ws + 4194304;             // (Kp region; Mf dead before Kp)
    float*  Kp     = ws + 4194304;             // 524,288
    float*  KWf    = ws + 4718592;             // (Vp region; KWf dead before Vp)
    float*  Vp     = ws + 4718592;             // 524,288
    double* KW     = (double*)(ws + 5242880);  // 1024*320 dbl
    int*    idx    = (int*)(ws + 5898240);     // 131,072
    double* inv_kd = (double*)(ws + 6029312);
    float*  inv_kf = ws + 6031360;
    float*  inv_vf = ws + 6032384;
    float*  qh     = Xreg;
    float*  co     = Xreg;                     // qh dead after attn
    float*  ctx    = Yreg;
    float2* stats  = (float2*)Yreg;            // ctx dead after co-gemm

    norms_kernel<<<2048, 256, 0, stream>>>(keys, vals, ln_g, inv_kd, inv_kf, inv_vf);
    gemm_ab_f64<<<dim3(5, 16), 256, 0, stream>>>(
        keys, Wqp, ln_g, inv_kd, KW, KWf, 1024, 320, 512);
    gemm_ab<<<dim3(5, 8), 256, 0, stream>>>(Wq, Wqp, ln_g, Mf, 512, 320, 512);
    // Sc = X @ KWf^T, 128x128 tile, grid 8x32 = 256 blocks
    gemm_sc128<<<dim3(8, 32), 256, 0, stream>>>(X, KWf, ln_g, Sc, 4096, 1024, 320);
    topk_select<<<1024, 256, 0, stream>>>(Sc, X, ln_g, KW, idx);
    gemm_abt<<<dim3(8, 64), 256, 0, stream>>>(
        X, Mf, nullptr, qh, nullptr, nullptr, 4096, 512, 320, 1, 0, 0, ln_g);
    gemm_kv<<<dim3(8, 32), 256, 0, stream>>>(
        keys, Wk, inv_kf, Kp, vals, Wv, inv_vf, Vp, ln_g);
    attn_kernel<<<4096, 256, 0, stream>>>(qh, Kp, Vp, idx, ctx);
    gemm_abt<<<dim3(8, 64), 256, 0, stream>>>(
        ctx, Wo, nullptr, co, nullptr, nullptr, 4096, 512, 512, 0, 1, 0, ln_g);
    ln_stats<<<1024, 256, 0, stream>>>(co, stats);
    gemm_out<<<dim3(5, 64), 256, 0, stream>>>(
        co, stats, ln_g, ln_b, Wout, bout, d_out, ln_g);
}